// Round 8
// baseline (7294.700 us; speedup 1.0000x reference)
//
#include <hip/hip_runtime.h>

typedef _Float16 f16;
typedef _Float16 half2t __attribute__((ext_vector_type(2)));
typedef _Float16 half8 __attribute__((ext_vector_type(8)));
typedef float f32x4 __attribute__((ext_vector_type(4)));

#define KP 320
#define DIN 300
#define SRAW 1024
#define SSUM 128
#define SCOPE_AGENT __HIP_MEMORY_SCOPE_AGENT

// ---------------- workspace layout (bytes) ----------------
static constexpr size_t OFF_XG_RAW  = 0;                                        // f16 [2][32][1024][1024] natural gate-major
static constexpr size_t OFF_XG_SUM  = OFF_XG_RAW + (size_t)2*32*1024*1024*2;    // f16 [2][32][128][1024]
static constexpr size_t OFF_OUT_RAW = OFF_XG_SUM + (size_t)2*32*128*1024*2;     // f16 [32][1024][512]
static constexpr size_t OFF_OUT_SUM = OFF_OUT_RAW + (size_t)32*1024*512*2;      // f16 [32][128][512]
static constexpr size_t OFF_A_RAW   = OFF_OUT_SUM + (size_t)32*128*512*2;       // f16 [32768][320]
static constexpr size_t OFF_A_SUM   = OFF_A_RAW + (size_t)32768*KP*2;           // f16 [4096][320]
static constexpr size_t OFF_BIH_RAW = OFF_A_SUM + (size_t)4096*KP*2;            // f16 [2048][320]
static constexpr size_t OFF_BIH_SUM = OFF_BIH_RAW + (size_t)2048*KP*2;          // f16 [2048][320]
static constexpr size_t OFF_WHH     = OFF_BIH_SUM + (size_t)2048*KP*2;          // f16 [4][2][1024][8][16]
static constexpr size_t OFF_WQ      = OFF_WHH + (size_t)4*2*1024*8*16*2;        // f16 [512][512]
static constexpr size_t OFF_KB      = OFF_WQ + (size_t)512*512*2;               // f32 [4][32][128]
static constexpr size_t OFF_VB      = OFF_KB + (size_t)4*32*128*4;              // f32 [4][32][128]
static constexpr size_t OFF_ATTN    = OFF_VB + (size_t)4*32*128*4;              // f32 [4][32][1024]
static constexpr size_t WS_NEED     = OFF_ATTN + (size_t)4*32*1024*4;           // ~208 MB
// lstm exchange aliases the bih region (dead after the input GEMMs):
static constexpr size_t OFF_XCHG    = OFF_BIH_RAW;                              // f32 [256][2][1024] = 2 MB
static constexpr size_t OFF_FLAGS   = OFF_BIH_RAW + (size_t)256*2*1024*4;       // u32 [256][16] = 16 KB

// ---------------- pack / convert ----------------
// Whh layout: [ed(4)][kh(2)][t(1024)][j(8)][i(16)] f16; thread t (rg=t>>3, ks=t&7)
// owns rows (t>>3)*8+j (== row t when ks==j) over k = kh*128 + ks*16 + i.
__global__ void pack_kernel(
    const float* __restrict__ in_raw, const float* __restrict__ in_sum,
    const float* __restrict__ wih_rf, const float* __restrict__ wih_rb,
    const float* __restrict__ wih_sf, const float* __restrict__ wih_sb,
    const float* __restrict__ whh_rf, const float* __restrict__ whh_rb,
    const float* __restrict__ whh_sf, const float* __restrict__ whh_sb,
    const float* __restrict__ wq,
    f16* __restrict__ a_raw, f16* __restrict__ a_sum,
    f16* __restrict__ bih_raw, f16* __restrict__ bih_sum,
    f16* __restrict__ whh16, f16* __restrict__ wq16)
{
  constexpr size_t N1 = (size_t)32768*KP;
  constexpr size_t N2 = (size_t)4096*KP;
  constexpr size_t N3 = (size_t)2048*KP;
  constexpr size_t N5 = (size_t)4*2*1024*8*16;
  constexpr size_t N6 = (size_t)512*512;
  const size_t TOT = N1+N2+N3+N3+N5+N6;
  const size_t stride = (size_t)gridDim.x*blockDim.x;
  for (size_t i = (size_t)blockIdx.x*blockDim.x + threadIdx.x; i < TOT; i += stride) {
    size_t j = i;
    if (j < N1) {
      size_t m = j/KP, k = j - m*KP;
      a_raw[j] = (f16)(k < DIN ? in_raw[m*DIN + k] : 0.f);
      continue;
    }
    j -= N1;
    if (j < N2) {
      size_t m = j/KP, k = j - m*KP;
      a_sum[j] = (f16)(k < DIN ? in_sum[m*DIN + k] : 0.f);
      continue;
    }
    j -= N2;
    if (j < N3) {
      size_t n = j/KP, k = j - n*KP;
      float v = 0.f;
      if (k < DIN) v = (n < 1024) ? wih_rf[n*DIN + k] : wih_rb[(n-1024)*DIN + k];
      bih_raw[j] = (f16)v;
      continue;
    }
    j -= N3;
    if (j < N3) {
      size_t n = j/KP, k = j - n*KP;
      float v = 0.f;
      if (k < DIN) v = (n < 1024) ? wih_sf[n*DIN + k] : wih_sb[(n-1024)*DIN + k];
      bih_sum[j] = (f16)v;
      continue;
    }
    j -= N3;
    if (j < N5) {
      int ed = (int)(j >> 18);
      int kh = (int)((j >> 17) & 1);
      int t  = (int)((j >> 7) & 1023);
      int jr = (int)((j >> 4) & 7);
      int ii = (int)(j & 15);
      int row = (t >> 3)*8 + jr;
      int col = kh*128 + (t & 7)*16 + ii;
      const float* src = (ed==0)?whh_rf:(ed==1)?whh_rb:(ed==2)?whh_sf:whh_sb;
      whh16[j] = (f16)src[(size_t)row*256 + col];
      continue;
    }
    j -= N5;
    {
      int n = (int)(j >> 9), k = (int)(j & 511);
      int h = n >> 7, dh = n & 127;
      wq16[j] = (f16)wq[((size_t)h*512 + k)*128 + dh];
    }
  }
}

// ---------------- zero pair-sync flags (every launch; replay-safe) ----------------
__global__ void zero_flags_kernel(unsigned* __restrict__ flags) {
  flags[blockIdx.x*1024 + threadIdx.x] = 0u;   // 4 blocks x 1024 = 4096 u32 = 16 KB
}

// ---------------- f16 MFMA GEMM: C[M,N] = A[M,K] * B[N,K]^T ----------------
template<int EPI>
__global__ __launch_bounds__(256) void gemm_kernel(
    const f16* __restrict__ A, const f16* __restrict__ Bm,
    float* __restrict__ Cf, f16* __restrict__ Cx,
    const float* __restrict__ bias0, const float* __restrict__ bias1,
    int K, int ldcN, size_t dirStride)
{
  __shared__ __align__(16) f16 As[128*40];
  __shared__ __align__(16) f16 Bs[128*40];
  const int tid = threadIdx.x;
  const int m0 = blockIdx.x*128, n0 = blockIdx.y*128;
  const int w = tid >> 6, lane = tid & 63;
  const int wm = w >> 1, wn = w & 1;
  const int lr = lane & 15, lk = lane >> 4;
  f32x4 acc[4][4] = {};
  const int nsteps = K >> 5;
  for (int kt = 0; kt < nsteps; ++kt) {
    __syncthreads();
    #pragma unroll
    for (int it = 0; it < 2; ++it) {
      int c = tid + it*256;
      int r = c >> 2, kc = c & 3;
      *(uint4*)&As[r*40 + kc*8] = *(const uint4*)&A[(size_t)(m0+r)*K + kt*32 + kc*8];
      *(uint4*)&Bs[r*40 + kc*8] = *(const uint4*)&Bm[(size_t)(n0+r)*K + kt*32 + kc*8];
    }
    __syncthreads();
    half8 af[4], bf[4];
    #pragma unroll
    for (int mt = 0; mt < 4; ++mt) af[mt] = *(const half8*)&As[(wm*64 + mt*16 + lr)*40 + lk*8];
    #pragma unroll
    for (int nt = 0; nt < 4; ++nt) bf[nt] = *(const half8*)&Bs[(wn*64 + nt*16 + lr)*40 + lk*8];
    #pragma unroll
    for (int mt = 0; mt < 4; ++mt)
      #pragma unroll
      for (int nt = 0; nt < 4; ++nt)
        acc[mt][nt] = __builtin_amdgcn_mfma_f32_16x16x32_f16(af[mt], bf[nt], acc[mt][nt], 0, 0, 0);
  }
  const int rb = lk*4;
  #pragma unroll
  for (int mt = 0; mt < 4; ++mt) {
    #pragma unroll
    for (int nt = 0; nt < 4; ++nt) {
      int n = n0 + wn*64 + nt*16 + lr;
      int mloc = m0 + wm*64 + mt*16 + rb;
      if (EPI == 0) {
        #pragma unroll
        for (int r = 0; r < 4; ++r)
          Cf[(size_t)(mloc+r)*ldcN + n] = acc[mt][nt][r];
      } else {
        int dir = n >> 10, cc = n & 1023;
        float bs = (dir ? bias1 : bias0)[cc];
        f16* dst = Cx + (size_t)dir*dirStride;
        #pragma unroll
        for (int r = 0; r < 4; ++r)
          dst[(size_t)(mloc+r)*1024 + cc] = (f16)(acc[mt][nt][r] + bs);
      }
    }
  }
}

// ---------------- LSTM recurrence: pair-split by k-halves ----------------
// 256 WGs x 1024 thr. wg: p=wg>>1 (recurrence e,d,b), kh=wg&1 (k-half).
// Thread t: rg=t>>3, ks=t&7; 8 rows rg*8+j, k in [kh*128+ks*16, +16).
// All weights register-resident (64 dw). Partial pre-acts (1024 f32) exchanged
// with partner WG via L2 (double-buffered by step parity + release/acquire flag).
// Both WGs redundantly compute the tail from bit-identical totals (a+b == b+a),
// so c/h state stays replicated and no h exchange is needed.

__device__ __forceinline__ float dot8(float acc, uint4 wv, uint4 hv) {
#if __has_builtin(__builtin_amdgcn_fdot2)
  union { uint4 u; half2t h[4]; } W, Hh;
  W.u = wv; Hh.u = hv;
  #pragma unroll
  for (int i = 0; i < 4; ++i) acc = __builtin_amdgcn_fdot2(W.h[i], Hh.h[i], acc, false);
#else
  union { uint4 u; f16 h[8]; } W, Hh;
  W.u = wv; Hh.u = hv;
  #pragma unroll
  for (int i = 0; i < 8; ++i) acc += (float)W.h[i]*(float)Hh.h[i];
#endif
  return acc;
}

__device__ __forceinline__ float sigmoid_f(float x) {
  float e = __expf(-x);
  return __builtin_amdgcn_rcpf(1.f + e);
}
__device__ __forceinline__ float tanh_f(float x) {
  float e = __expf(2.f * x);
  return 1.f - 2.f * __builtin_amdgcn_rcpf(e + 1.f);
}

__device__ __forceinline__ void pin4(uint4& v) {
  asm volatile("" : "+v"(v.x), "+v"(v.y), "+v"(v.z), "+v"(v.w));
}

template<int CTRL>
__device__ __forceinline__ float dpp_add(float v) {
  int m = __builtin_amdgcn_update_dpp(0, __builtin_bit_cast(int, v), CTRL, 0xf, 0xf, true);
  return v + __builtin_bit_cast(float, m);
}
__device__ __forceinline__ float reduce8(float v) {
  v = dpp_add<0xB1>(v);   // lane ^ 1
  v = dpp_add<0x4E>(v);   // lane ^ 2
  v = dpp_add<0x141>(v);  // row_half_mirror: lane ^ (cross 4-group within 8)
  return v;
}

__global__ void __launch_bounds__(1024)
lstm_kernel(
    const f16* __restrict__ whh16,
    const f16* __restrict__ xg_raw, const f16* __restrict__ xg_sum,
    f16* __restrict__ out_raw, f16* __restrict__ out_sum,
    float* __restrict__ xchg, unsigned* __restrict__ flags)
{
  const int wg = blockIdx.x;             // [p(7)][kh(1)]
  const int p = wg >> 1, kh = wg & 1;
  const int e = p >> 6, d = (p >> 5) & 1, b = p & 31;
  const int S = e ? SSUM : SRAW;
  const int t = threadIdx.x;
  const int ks = t & 7;

  const uint4* wb = (const uint4*)whh16 + ((size_t)((e*2+d)*2 + kh)*1024 + t)*16;
  const f16* xg = (e ? xg_sum : xg_raw) + ((size_t)(d*32 + b))*(size_t)S*1024;
  f16* outp = (e ? out_sum : out_raw) + (size_t)b*S*512 + d*256;

  float* xc_mine    = xchg + (size_t)wg*2048;
  const float* xc_p = xchg + (size_t)(wg ^ 1)*2048;
  unsigned* flag_mine    = flags + (size_t)wg*16;
  const unsigned* flag_p = flags + (size_t)(wg ^ 1)*16;

  __shared__ float preL[1024];           // activated gate values
  __shared__ __align__(16) f16 hl[256];  // replicated h state

  // all weights in registers (16 uint4 = 64 dw), pinned
  uint4 wr[16];
  #pragma unroll
  for (int c = 0; c < 16; ++c) wr[c] = wb[c];
  #pragma unroll
  for (int c = 0; c < 16; ++c) pin4(wr[c]);

  if (t < 256) hl[t] = (f16)0.f;
  float cst = 0.f;
  const int hbyte = kh*256 + ks*32;      // own k-half slice; 2-way bank alias = free
  const bool isG = ((t >> 8) == 2);
  __syncthreads();

  for (int st = 0; st < S; ++st) {
    const int s = d ? (S - 1 - st) : st;
    const int par = st & 1;

    float xv = (float)xg[(size_t)s*1024 + t];

    uint4 hv0 = *(const uint4*)((const char*)hl + hbyte);
    uint4 hv1 = *(const uint4*)((const char*)hl + hbyte + 16);

    float po = 0.f;                      // own-half partial for row t
    #pragma unroll
    for (int j = 0; j < 8; ++j) {
      float rs = dot8(0.f, wr[j*2], hv0);
      rs = dot8(rs, wr[j*2 + 1], hv1);
      rs = reduce8(rs);
      po = (ks == j) ? rs : po;
    }

    // publish own partial (double-buffered by parity)
    __hip_atomic_store(&xc_mine[par*1024 + t], po, __ATOMIC_RELAXED, SCOPE_AGENT);
    __syncthreads();                     // drains all waves' stores before flag
    if (t == 0) {
      __threadfence();
      __hip_atomic_store(flag_mine, (unsigned)(st + 1), __ATOMIC_RELEASE, SCOPE_AGENT);
      while (__hip_atomic_load(flag_p, __ATOMIC_ACQUIRE, SCOPE_AGENT) < (unsigned)(st + 1))
        __builtin_amdgcn_s_sleep(2);
    }
    __syncthreads();

    float pp = __hip_atomic_load(&xc_p[par*1024 + t], __ATOMIC_RELAXED, SCOPE_AGENT);
    float v = po + pp + xv;              // commutative: bit-identical in both WGs
    preL[t] = isG ? tanh_f(v) : sigmoid_f(v);
    __syncthreads();

    if (t < 256) {                       // replicated tail; identical in both WGs
      float ig = preL[t], fg = preL[256 + t], gg = preL[512 + t], og = preL[768 + t];
      cst = fg*cst + ig*gg;
      float hval = og*tanh_f(cst);
      f16 hf = (f16)hval;
      hl[t] = hf;
      if (kh == 0) outp[(size_t)s*512 + t] = hf;
    }
    __syncthreads();
  }
}

// ---------------- mean pool + k,v projection ----------------
__global__ __launch_bounds__(256) void pool_kv_kernel(
    const f16* __restrict__ out_sum, const int* __restrict__ len_sum,
    const float* __restrict__ Wk, const float* __restrict__ Wv,
    float* __restrict__ kb, float* __restrict__ vb)
{
  const int b = blockIdx.x, t = threadIdx.x;
  __shared__ float sv[512];
  int len = len_sum[b]; if (len < 1) len = 1;
  float a0 = 0.f, a1 = 0.f;
  for (int s = 0; s < len; ++s) {
    const f16* row = out_sum + ((size_t)b*SSUM + s)*512;
    a0 += (float)row[t];
    a1 += (float)row[t+256];
  }
  float inv = 1.f/(float)len;
  sv[t] = a0*inv; sv[t+256] = a1*inv;
  __syncthreads();
  #pragma unroll
  for (int half = 0; half < 2; ++half) {
    int o = t + half*256;
    int h = o >> 7, dh = o & 127;
    const float* wkp = Wk + (size_t)h*512*128 + dh;
    const float* wvp = Wv + (size_t)h*512*128 + dh;
    float ak = 0.f, av = 0.f;
    for (int e2 = 0; e2 < 512; ++e2) {
      float sve = sv[e2];
      ak += sve*wkp[(size_t)e2*128];
      av += sve*wvp[(size_t)e2*128];
    }
    kb[((size_t)h*32 + b)*128 + dh] = ak;
    vb[((size_t)h*32 + b)*128 + dh] = av;
  }
}

// ---------------- scores + softmax ----------------
__global__ __launch_bounds__(256) void attn_kernel(
    const float* __restrict__ q, const float* __restrict__ kb, float* __restrict__ attn)
{
  const int hb = blockIdx.x;          // h*32 + b
  const int h = hb >> 5, b = hb & 31;
  const int t = threadIdx.x;
  __shared__ __align__(16) float kk[128];
  __shared__ float red[4];
  if (t < 128) kk[t] = kb[(size_t)hb*128 + t];
  __syncthreads();
  float vals[4];
  #pragma unroll
  for (int i = 0; i < 4; ++i) {
    int s = t + i*256;
    const float4* qp = (const float4*)(q + ((size_t)b*1024 + s)*512 + h*128);
    const float4* kp = (const float4*)kk;
    float a = 0.f;
    #pragma unroll
    for (int e2 = 0; e2 < 32; ++e2) {
      float4 qq = qp[e2], kx = kp[e2];
      a += qq.x*kx.x + qq.y*kx.y + qq.z*kx.z + qq.w*kx.w;
    }
    vals[i] = a;
  }
  float m = fmaxf(fmaxf(vals[0], vals[1]), fmaxf(vals[2], vals[3]));
  for (int o = 1; o < 64; o <<= 1) m = fmaxf(m, __shfl_xor(m, o));
  if ((t & 63) == 0) red[t >> 6] = m;
  __syncthreads();
  m = fmaxf(fmaxf(red[0], red[1]), fmaxf(red[2], red[3]));
  __syncthreads();
  float ex[4], lsum = 0.f;
  #pragma unroll
  for (int i = 0; i < 4; ++i) { ex[i] = __expf(vals[i] - m); lsum += ex[i]; }
  for (int o = 1; o < 64; o <<= 1) lsum += __shfl_xor(lsum, o);
  if ((t & 63) == 0) red[t >> 6] = lsum;
  __syncthreads();
  float inv = 1.f/(red[0] + red[1] + red[2] + red[3]);
  #pragma unroll
  for (int i = 0; i < 4; ++i) attn[(size_t)hb*1024 + t + i*256] = ex[i]*inv;
}

// ---------------- final: out = q + attn * v ----------------
__global__ __launch_bounds__(256) void final_kernel(
    float* __restrict__ out, const float* __restrict__ attn, const float* __restrict__ vb)
{
  const size_t TOT4 = (size_t)32*1024*512/4;
  const size_t stride = (size_t)gridDim.x*blockDim.x;
  for (size_t i = (size_t)blockIdx.x*blockDim.x + threadIdx.x; i < TOT4; i += stride) {
    int c4 = (int)(i & 127);
    int h = c4 >> 5;
    size_t srow = i >> 7;
    int b = (int)(srow >> 10), s = (int)(srow & 1023);
    float a = attn[((size_t)h*32 + b)*1024 + s];
    float4 vv = ((const float4*)vb)[((size_t)h*32 + b)*32 + (c4 & 31)];
    float4 qq = ((float4*)out)[i];
    qq.x += a*vv.x; qq.y += a*vv.y; qq.z += a*vv.z; qq.w += a*vv.w;
    ((float4*)out)[i] = qq;
  }
}

// ---------------- launch ----------------
extern "C" void kernel_launch(void* const* d_in, const int* in_sizes, int n_in,
                              void* d_out, int out_size, void* d_ws, size_t ws_size,
                              hipStream_t stream)
{
  const float* in_raw = (const float*)d_in[0];
  const float* in_sum = (const float*)d_in[1];
  const int*  len_sum = (const int*)d_in[3];
  const float* rf_wih = (const float*)d_in[4];
  const float* rf_whh = (const float*)d_in[5];
  const float* rf_b   = (const float*)d_in[6];
  const float* rb_wih = (const float*)d_in[7];
  const float* rb_whh = (const float*)d_in[8];
  const float* rb_b   = (const float*)d_in[9];
  const float* sf_wih = (const float*)d_in[10];
  const float* sf_whh = (const float*)d_in[11];
  const float* sf_b   = (const float*)d_in[12];
  const float* sb_wih = (const float*)d_in[13];
  const float* sb_whh = (const float*)d_in[14];
  const float* sb_b   = (const float*)d_in[15];
  const float* wq     = (const float*)d_in[16];
  const float* wk     = (const float*)d_in[17];
  const float* wv     = (const float*)d_in[18];

  if (ws_size < WS_NEED) return;

  char* ws = (char*)d_ws;
  f16* xg_raw_p  = (f16*)(ws + OFF_XG_RAW);
  f16* xg_sum_p  = (f16*)(ws + OFF_XG_SUM);
  f16* out_raw_p = (f16*)(ws + OFF_OUT_RAW);
  f16* out_sum_p = (f16*)(ws + OFF_OUT_SUM);
  f16* a_raw_p   = (f16*)(ws + OFF_A_RAW);
  f16* a_sum_p   = (f16*)(ws + OFF_A_SUM);
  f16* bih_raw_p = (f16*)(ws + OFF_BIH_RAW);
  f16* bih_sum_p = (f16*)(ws + OFF_BIH_SUM);
  f16* whh16_p   = (f16*)(ws + OFF_WHH);
  f16* wq16_p    = (f16*)(ws + OFF_WQ);
  float* kb_p    = (float*)(ws + OFF_KB);
  float* vb_p    = (float*)(ws + OFF_VB);
  float* attn_p  = (float*)(ws + OFF_ATTN);
  float* xchg_p  = (float*)(ws + OFF_XCHG);
  unsigned* flags_p = (unsigned*)(ws + OFF_FLAGS);
  float* qout    = (float*)d_out;

  pack_kernel<<<4096, 256, 0, stream>>>(
      in_raw, in_sum, rf_wih, rb_wih, sf_wih, sb_wih,
      rf_whh, rb_whh, sf_whh, sb_whh, wq,
      a_raw_p, a_sum_p, bih_raw_p, bih_sum_p, whh16_p, wq16_p);

  gemm_kernel<1><<<dim3(256, 16), 256, 0, stream>>>(
      a_raw_p, bih_raw_p, nullptr, xg_raw_p, rf_b, rb_b, KP, 0, (size_t)32*1024*1024);
  gemm_kernel<1><<<dim3(32, 16), 256, 0, stream>>>(
      a_sum_p, bih_sum_p, nullptr, xg_sum_p, sf_b, sb_b, KP, 0, (size_t)32*128*1024);

  // bih region is dead from here; its space hosts xchg + flags for the lstm.
  zero_flags_kernel<<<4, 1024, 0, stream>>>(flags_p);

  lstm_kernel<<<256, 1024, 0, stream>>>(whh16_p, xg_raw_p, xg_sum_p,
                                        out_raw_p, out_sum_p, xchg_p, flags_p);

  gemm_kernel<0><<<dim3(256, 4), 256, 0, stream>>>(
      out_raw_p, wq16_p, qout, nullptr, nullptr, nullptr, 512, 512, 0);

  pool_kv_kernel<<<32, 256, 0, stream>>>(out_sum_p, len_sum, wk, wv, kb_p, vb_p);
  attn_kernel<<<128, 256, 0, stream>>>(qout, kb_p, attn_p);
  final_kernel<<<4096, 256, 0, stream>>>(qout, attn_p, vb_p);
}

// Round 9
// 3095.471 us; speedup vs baseline: 2.3566x; 2.3566x over previous
//
#include <hip/hip_runtime.h>

typedef _Float16 f16;
typedef _Float16 half2t __attribute__((ext_vector_type(2)));
typedef _Float16 half8 __attribute__((ext_vector_type(8)));
typedef float f32x4 __attribute__((ext_vector_type(4)));

#define KP 320
#define DIN 300
#define SRAW 1024
#define SSUM 128

// ---------------- workspace layout (bytes) ----------------
static constexpr size_t OFF_XG_RAW  = 0;                                        // f16 [2][32][1024][1024] natural gate-major
static constexpr size_t OFF_XG_SUM  = OFF_XG_RAW + (size_t)2*32*1024*1024*2;    // f16 [2][32][128][1024]
static constexpr size_t OFF_OUT_RAW = OFF_XG_SUM + (size_t)2*32*128*1024*2;     // f16 [32][1024][512]
static constexpr size_t OFF_OUT_SUM = OFF_OUT_RAW + (size_t)32*1024*512*2;      // f16 [32][128][512]
static constexpr size_t OFF_A_RAW   = OFF_OUT_SUM + (size_t)32*128*512*2;       // f16 [32768][320]
static constexpr size_t OFF_A_SUM   = OFF_A_RAW + (size_t)32768*KP*2;           // f16 [4096][320]
static constexpr size_t OFF_BIH_RAW = OFF_A_SUM + (size_t)4096*KP*2;            // f16 [2048][320]
static constexpr size_t OFF_BIH_SUM = OFF_BIH_RAW + (size_t)2048*KP*2;          // f16 [2048][320]
static constexpr size_t OFF_WHH     = OFF_BIH_SUM + (size_t)2048*KP*2;          // f16 [4][128][256][8] chunk layout
static constexpr size_t OFF_WQ      = OFF_WHH + (size_t)4*128*256*8*2;          // f16 [512][512]
static constexpr size_t OFF_KB      = OFF_WQ + (size_t)512*512*2;               // f32 [4][32][128]
static constexpr size_t OFF_VB      = OFF_KB + (size_t)4*32*128*4;              // f32 [4][32][128]
static constexpr size_t OFF_ATTN    = OFF_VB + (size_t)4*32*128*4;              // f32 [4][32][1024]
static constexpr size_t WS_NEED     = OFF_ATTN + (size_t)4*32*1024*4;           // ~208 MB

// ---------------- pack / convert ----------------
// Whh chunk layout: [ed(4)][c(128)][t(256)][8 f16]; thread t (rg=t>>3, ks=t&7),
// chunk c = j*4+q holds W[rg*32+j][ks*32+q*8 .. +8), j in [0,32), q in [0,4).
__global__ void pack_kernel(
    const float* __restrict__ in_raw, const float* __restrict__ in_sum,
    const float* __restrict__ wih_rf, const float* __restrict__ wih_rb,
    const float* __restrict__ wih_sf, const float* __restrict__ wih_sb,
    const float* __restrict__ whh_rf, const float* __restrict__ whh_rb,
    const float* __restrict__ whh_sf, const float* __restrict__ whh_sb,
    const float* __restrict__ wq,
    f16* __restrict__ a_raw, f16* __restrict__ a_sum,
    f16* __restrict__ bih_raw, f16* __restrict__ bih_sum,
    f16* __restrict__ whh16, f16* __restrict__ wq16)
{
  constexpr size_t N1 = (size_t)32768*KP;
  constexpr size_t N2 = (size_t)4096*KP;
  constexpr size_t N3 = (size_t)2048*KP;
  constexpr size_t N5 = (size_t)4*128*256*8;
  constexpr size_t N6 = (size_t)512*512;
  const size_t TOT = N1+N2+N3+N3+N5+N6;
  const size_t stride = (size_t)gridDim.x*blockDim.x;
  for (size_t i = (size_t)blockIdx.x*blockDim.x + threadIdx.x; i < TOT; i += stride) {
    size_t j = i;
    if (j < N1) {
      size_t m = j/KP, k = j - m*KP;
      a_raw[j] = (f16)(k < DIN ? in_raw[m*DIN + k] : 0.f);
      continue;
    }
    j -= N1;
    if (j < N2) {
      size_t m = j/KP, k = j - m*KP;
      a_sum[j] = (f16)(k < DIN ? in_sum[m*DIN + k] : 0.f);
      continue;
    }
    j -= N2;
    if (j < N3) {
      size_t n = j/KP, k = j - n*KP;
      float v = 0.f;
      if (k < DIN) v = (n < 1024) ? wih_rf[n*DIN + k] : wih_rb[(n-1024)*DIN + k];
      bih_raw[j] = (f16)v;
      continue;
    }
    j -= N3;
    if (j < N3) {
      size_t n = j/KP, k = j - n*KP;
      float v = 0.f;
      if (k < DIN) v = (n < 1024) ? wih_sf[n*DIN + k] : wih_sb[(n-1024)*DIN + k];
      bih_sum[j] = (f16)v;
      continue;
    }
    j -= N3;
    if (j < N5) {
      int ed = (int)(j >> 18);
      int c  = (int)((j >> 11) & 127);
      int t  = (int)((j >> 3) & 255);
      int ii = (int)(j & 7);
      int jrow = c >> 2, q = c & 3;
      int rg = t >> 3, ks = t & 7;
      int row = rg*32 + jrow;
      int col = ks*32 + q*8 + ii;
      const float* src = (ed==0)?whh_rf:(ed==1)?whh_rb:(ed==2)?whh_sf:whh_sb;
      whh16[j] = (f16)src[(size_t)row*256 + col];
      continue;
    }
    j -= N5;
    {
      int n = (int)(j >> 9), k = (int)(j & 511);
      int h = n >> 7, dh = n & 127;
      wq16[j] = (f16)wq[((size_t)h*512 + k)*128 + dh];
    }
  }
}

// ---------------- f16 MFMA GEMM: C[M,N] = A[M,K] * B[N,K]^T ----------------
template<int EPI>
__global__ __launch_bounds__(256) void gemm_kernel(
    const f16* __restrict__ A, const f16* __restrict__ Bm,
    float* __restrict__ Cf, f16* __restrict__ Cx,
    const float* __restrict__ bias0, const float* __restrict__ bias1,
    int K, int ldcN, size_t dirStride)
{
  __shared__ __align__(16) f16 As[128*40];
  __shared__ __align__(16) f16 Bs[128*40];
  const int tid = threadIdx.x;
  const int m0 = blockIdx.x*128, n0 = blockIdx.y*128;
  const int w = tid >> 6, lane = tid & 63;
  const int wm = w >> 1, wn = w & 1;
  const int lr = lane & 15, lk = lane >> 4;
  f32x4 acc[4][4] = {};
  const int nsteps = K >> 5;
  for (int kt = 0; kt < nsteps; ++kt) {
    __syncthreads();
    #pragma unroll
    for (int it = 0; it < 2; ++it) {
      int c = tid + it*256;
      int r = c >> 2, kc = c & 3;
      *(uint4*)&As[r*40 + kc*8] = *(const uint4*)&A[(size_t)(m0+r)*K + kt*32 + kc*8];
      *(uint4*)&Bs[r*40 + kc*8] = *(const uint4*)&Bm[(size_t)(n0+r)*K + kt*32 + kc*8];
    }
    __syncthreads();
    half8 af[4], bf[4];
    #pragma unroll
    for (int mt = 0; mt < 4; ++mt) af[mt] = *(const half8*)&As[(wm*64 + mt*16 + lr)*40 + lk*8];
    #pragma unroll
    for (int nt = 0; nt < 4; ++nt) bf[nt] = *(const half8*)&Bs[(wn*64 + nt*16 + lr)*40 + lk*8];
    #pragma unroll
    for (int mt = 0; mt < 4; ++mt)
      #pragma unroll
      for (int nt = 0; nt < 4; ++nt)
        acc[mt][nt] = __builtin_amdgcn_mfma_f32_16x16x32_f16(af[mt], bf[nt], acc[mt][nt], 0, 0, 0);
  }
  const int rb = lk*4;
  #pragma unroll
  for (int mt = 0; mt < 4; ++mt) {
    #pragma unroll
    for (int nt = 0; nt < 4; ++nt) {
      int n = n0 + wn*64 + nt*16 + lr;
      int mloc = m0 + wm*64 + mt*16 + rb;
      if (EPI == 0) {
        #pragma unroll
        for (int r = 0; r < 4; ++r)
          Cf[(size_t)(mloc+r)*ldcN + n] = acc[mt][nt][r];
      } else {
        int dir = n >> 10, cc = n & 1023;
        float bs = (dir ? bias1 : bias0)[cc];
        f16* dst = Cx + (size_t)dir*dirStride;
        #pragma unroll
        for (int r = 0; r < 4; ++r)
          dst[(size_t)(mloc+r)*1024 + cc] = (f16)(acc[mt][nt][r] + bs);
      }
    }
  }
}

// ---------------- LSTM recurrence: T=256, weights register-resident ----------------
// 1 WG (256 thr, 4 waves = 1/SIMD) per (e,d,b). Thread t: rg=t>>3, ks=t&7.
// Owns 32 gate rows rg*32+j (j=0..31) over k-slice [ks*32, ks*32+32).
// j=0..28 in registers (116 uint4 = 464 dw), j=29..31 from LDS (48 KB).
// Zero per-step L2 weight traffic. Tail: thread u handles unit u.
#define RROWS 29
#define LROWS 3

__device__ __forceinline__ float dot8(float acc, uint4 wv, uint4 hv) {
#if __has_builtin(__builtin_amdgcn_fdot2)
  union { uint4 u; half2t h[4]; } W, Hh;
  W.u = wv; Hh.u = hv;
  #pragma unroll
  for (int i = 0; i < 4; ++i) acc = __builtin_amdgcn_fdot2(W.h[i], Hh.h[i], acc, false);
#else
  union { uint4 u; f16 h[8]; } W, Hh;
  W.u = wv; Hh.u = hv;
  #pragma unroll
  for (int i = 0; i < 8; ++i) acc += (float)W.h[i]*(float)Hh.h[i];
#endif
  return acc;
}

__device__ __forceinline__ float sigmoid_f(float x) {
  float e = __expf(-x);
  return __builtin_amdgcn_rcpf(1.f + e);
}
__device__ __forceinline__ float tanh_f(float x) {
  float e = __expf(2.f * x);
  return 1.f - 2.f * __builtin_amdgcn_rcpf(e + 1.f);
}

template<int CTRL>
__device__ __forceinline__ float dpp_add(float v) {
  int m = __builtin_amdgcn_update_dpp(0, __builtin_bit_cast(int, v), CTRL, 0xf, 0xf, true);
  return v + __builtin_bit_cast(float, m);
}
__device__ __forceinline__ float reduce8(float v) {
  v = dpp_add<0xB1>(v);   // lane ^ 1
  v = dpp_add<0x4E>(v);   // lane ^ 2
  v = dpp_add<0x141>(v);  // row_half_mirror (crosses the 4-group within 8)
  return v;
}

__global__ void __launch_bounds__(256)
lstm_kernel(
    const f16* __restrict__ whh16,
    const f16* __restrict__ xg_raw, const f16* __restrict__ xg_sum,
    f16* __restrict__ out_raw, f16* __restrict__ out_sum)
{
  const int wg = blockIdx.x;               // [e(1)][d(1)][b(5)]
  const int e = wg >> 6, d = (wg >> 5) & 1, b = wg & 31;
  const int S = e ? SSUM : SRAW;
  const int t = threadIdx.x;
  const int rg = t >> 3, ks = t & 7;
  const uint4* wb = (const uint4*)whh16 + (size_t)(e*2+d)*(128*256);
  const f16* xg = (e ? xg_sum : xg_raw) + ((size_t)(d*32 + b))*(size_t)S*1024;
  f16* outp = (e ? out_sum : out_raw) + (size_t)b*S*512 + d*256;

  __shared__ __align__(16) uint4 wl[LROWS*4*256];   // 48 KB: rows 29..31
  __shared__ float preL[1024];                       // raw->activated gate values
  __shared__ __align__(16) char hl8[8*72];           // h[256] in 8 chunks, 72B stride

  // stage LDS weight rows 29..31 (chunks 116..127)
  #pragma unroll
  for (int c = 0; c < LROWS*4; ++c) wl[c*256 + t] = wb[(RROWS*4 + c)*256 + t];
  // register weight rows 0..28 (chunks 0..115); ~464 dw/thread, no occupancy
  // pressure at 4 waves/CU so loads stay hoisted (no pin: "+v" would force
  // arch regs and churn copies; AGPR residency is fine).
  uint4 wr[RROWS*4];
  #pragma unroll
  for (int c = 0; c < RROWS*4; ++c) wr[c] = wb[c*256 + t];

  // zero h chunks (576 B)
  for (int i = t; i < 144; i += 256) ((unsigned*)hl8)[i] = 0u;
  float cst = 0.f;
  const int hbyte = ks*72;                  // padded chunk stride: <=2-way alias (free)
  const bool isG = ((t >> 6) == 2);         // rows rg*32.. all share gate = t>>6
  const int row0 = rg*32 + ks;              // own rows: row0 + 8m, m=0..3

  // prologue xg for step 0
  const int s0 = d ? (S - 1) : 0;
  f16 xc[4];
  #pragma unroll
  for (int m = 0; m < 4; ++m) xc[m] = xg[(size_t)s0*1024 + row0 + 8*m];
  __syncthreads();

  for (int st = 0; st < S; ++st) {
    const int s = d ? (S - 1 - st) : st;

    // prefetch next step's xg
    f16 xn[4] = {(f16)0.f, (f16)0.f, (f16)0.f, (f16)0.f};
    if (st + 1 < S) {
      const int sn = d ? (S - 2 - st) : (st + 1);
      #pragma unroll
      for (int m = 0; m < 4; ++m) xn[m] = xg[(size_t)sn*1024 + row0 + 8*m];
    }

    // h slice (32 f16) from padded chunks
    uint4 hv[4];
    #pragma unroll
    for (int q = 0; q < 4; ++q)
      hv[q] = *(const uint4*)(hl8 + hbyte + q*16);

    float p[4] = {0.f, 0.f, 0.f, 0.f};

    // register rows 0..28
    #pragma unroll
    for (int j = 0; j < RROWS; ++j) {
      float rs = 0.f;
      #pragma unroll
      for (int q = 0; q < 4; ++q) rs = dot8(rs, wr[j*4 + q], hv[q]);
      rs = reduce8(rs);
      if (ks == (j & 7)) p[j >> 3] = rs;
    }
    // LDS rows 29..31
    #pragma unroll
    for (int j = RROWS; j < 32; ++j) {
      float rs = 0.f;
      #pragma unroll
      for (int q = 0; q < 4; ++q) rs = dot8(rs, wl[((j - RROWS)*4 + q)*256 + t], hv[q]);
      rs = reduce8(rs);
      if (ks == (j & 7)) p[j >> 3] = rs;
    }

    // distributed activation (gate type wave-uniform), store to preL
    #pragma unroll
    for (int m = 0; m < 4; ++m) {
      float v = p[m] + (float)xc[m];
      float a = isG ? tanh_f(v) : sigmoid_f(v);
      preL[row0 + 8*m] = a;
      xc[m] = xn[m];
    }
    __syncthreads();

    // tail: thread u = t owns unit u
    {
      float ig = preL[t], fg = preL[256 + t], gg = preL[512 + t], og = preL[768 + t];
      cst = fg*cst + ig*gg;
      float hval = og*tanh_f(cst);
      f16 hf = (f16)hval;
      *(f16*)(hl8 + (t >> 5)*72 + (t & 31)*2) = hf;
      outp[(size_t)s*512 + t] = hf;
    }
    __syncthreads();
  }
}

// ---------------- mean pool + k,v projection ----------------
__global__ __launch_bounds__(256) void pool_kv_kernel(
    const f16* __restrict__ out_sum, const int* __restrict__ len_sum,
    const float* __restrict__ Wk, const float* __restrict__ Wv,
    float* __restrict__ kb, float* __restrict__ vb)
{
  const int b = blockIdx.x, t = threadIdx.x;
  __shared__ float sv[512];
  int len = len_sum[b]; if (len < 1) len = 1;
  float a0 = 0.f, a1 = 0.f;
  for (int s = 0; s < len; ++s) {
    const f16* row = out_sum + ((size_t)b*SSUM + s)*512;
    a0 += (float)row[t];
    a1 += (float)row[t+256];
  }
  float inv = 1.f/(float)len;
  sv[t] = a0*inv; sv[t+256] = a1*inv;
  __syncthreads();
  #pragma unroll
  for (int half = 0; half < 2; ++half) {
    int o = t + half*256;
    int h = o >> 7, dh = o & 127;
    const float* wkp = Wk + (size_t)h*512*128 + dh;
    const float* wvp = Wv + (size_t)h*512*128 + dh;
    float ak = 0.f, av = 0.f;
    for (int e2 = 0; e2 < 512; ++e2) {
      float sve = sv[e2];
      ak += sve*wkp[(size_t)e2*128];
      av += sve*wvp[(size_t)e2*128];
    }
    kb[((size_t)h*32 + b)*128 + dh] = ak;
    vb[((size_t)h*32 + b)*128 + dh] = av;
  }
}

// ---------------- scores + softmax ----------------
__global__ __launch_bounds__(256) void attn_kernel(
    const float* __restrict__ q, const float* __restrict__ kb, float* __restrict__ attn)
{
  const int hb = blockIdx.x;          // h*32 + b
  const int h = hb >> 5, b = hb & 31;
  const int t = threadIdx.x;
  __shared__ __align__(16) float kk[128];
  __shared__ float red[4];
  if (t < 128) kk[t] = kb[(size_t)hb*128 + t];
  __syncthreads();
  float vals[4];
  #pragma unroll
  for (int i = 0; i < 4; ++i) {
    int s = t + i*256;
    const float4* qp = (const float4*)(q + ((size_t)b*1024 + s)*512 + h*128);
    const float4* kp = (const float4*)kk;
    float a = 0.f;
    #pragma unroll
    for (int e2 = 0; e2 < 32; ++e2) {
      float4 qq = qp[e2], kx = kp[e2];
      a += qq.x*kx.x + qq.y*kx.y + qq.z*kx.z + qq.w*kx.w;
    }
    vals[i] = a;
  }
  float m = fmaxf(fmaxf(vals[0], vals[1]), fmaxf(vals[2], vals[3]));
  for (int o = 1; o < 64; o <<= 1) m = fmaxf(m, __shfl_xor(m, o));
  if ((t & 63) == 0) red[t >> 6] = m;
  __syncthreads();
  m = fmaxf(fmaxf(red[0], red[1]), fmaxf(red[2], red[3]));
  __syncthreads();
  float ex[4], lsum = 0.f;
  #pragma unroll
  for (int i = 0; i < 4; ++i) { ex[i] = __expf(vals[i] - m); lsum += ex[i]; }
  for (int o = 1; o < 64; o <<= 1) lsum += __shfl_xor(lsum, o);
  if ((t & 63) == 0) red[t >> 6] = lsum;
  __syncthreads();
  float inv = 1.f/(red[0] + red[1] + red[2] + red[3]);
  #pragma unroll
  for (int i = 0; i < 4; ++i) attn[(size_t)hb*1024 + t + i*256] = ex[i]*inv;
}

// ---------------- final: out = q + attn * v ----------------
__global__ __launch_bounds__(256) void final_kernel(
    float* __restrict__ out, const float* __restrict__ attn, const float* __restrict__ vb)
{
  const size_t TOT4 = (size_t)32*1024*512/4;
  const size_t stride = (size_t)gridDim.x*blockDim.x;
  for (size_t i = (size_t)blockIdx.x*blockDim.x + threadIdx.x; i < TOT4; i += stride) {
    int c4 = (int)(i & 127);
    int h = c4 >> 5;
    size_t srow = i >> 7;
    int b = (int)(srow >> 10), s = (int)(srow & 1023);
    float a = attn[((size_t)h*32 + b)*1024 + s];
    float4 vv = ((const float4*)vb)[((size_t)h*32 + b)*32 + (c4 & 31)];
    float4 qq = ((float4*)out)[i];
    qq.x += a*vv.x; qq.y += a*vv.y; qq.z += a*vv.z; qq.w += a*vv.w;
    ((float4*)out)[i] = qq;
  }
}

// ---------------- launch ----------------
extern "C" void kernel_launch(void* const* d_in, const int* in_sizes, int n_in,
                              void* d_out, int out_size, void* d_ws, size_t ws_size,
                              hipStream_t stream)
{
  const float* in_raw = (const float*)d_in[0];
  const float* in_sum = (const float*)d_in[1];
  const int*  len_sum = (const int*)d_in[3];
  const float* rf_wih = (const float*)d_in[4];
  const float* rf_whh = (const float*)d_in[5];
  const float* rf_b   = (const float*)d_in[6];
  const float* rb_wih = (const float*)d_in[7];
  const float* rb_whh = (const float*)d_in[8];
  const float* rb_b   = (const float*)d_in[9];
  const float* sf_wih = (const float*)d_in[10];
  const float* sf_whh = (const float*)d_in[11];
  const float* sf_b   = (const float*)d_in[12];
  const float* sb_wih = (const float*)d_in[13];
  const float* sb_whh = (const float*)d_in[14];
  const float* sb_b   = (const float*)d_in[15];
  const float* wq     = (const float*)d_in[16];
  const float* wk     = (const float*)d_in[17];
  const float* wv     = (const float*)d_in[18];

  if (ws_size < WS_NEED) return;

  char* ws = (char*)d_ws;
  f16* xg_raw_p  = (f16*)(ws + OFF_XG_RAW);
  f16* xg_sum_p  = (f16*)(ws + OFF_XG_SUM);
  f16* out_raw_p = (f16*)(ws + OFF_OUT_RAW);
  f16* out_sum_p = (f16*)(ws + OFF_OUT_SUM);
  f16* a_raw_p   = (f16*)(ws + OFF_A_RAW);
  f16* a_sum_p   = (f16*)(ws + OFF_A_SUM);
  f16* bih_raw_p = (f16*)(ws + OFF_BIH_RAW);
  f16* bih_sum_p = (f16*)(ws + OFF_BIH_SUM);
  f16* whh16_p   = (f16*)(ws + OFF_WHH);
  f16* wq16_p    = (f16*)(ws + OFF_WQ);
  float* kb_p    = (float*)(ws + OFF_KB);
  float* vb_p    = (float*)(ws + OFF_VB);
  float* attn_p  = (float*)(ws + OFF_ATTN);
  float* qout    = (float*)d_out;

  pack_kernel<<<4096, 256, 0, stream>>>(
      in_raw, in_sum, rf_wih, rb_wih, sf_wih, sb_wih,
      rf_whh, rb_whh, sf_whh, sb_whh, wq,
      a_raw_p, a_sum_p, bih_raw_p, bih_sum_p, whh16_p, wq16_p);

  gemm_kernel<1><<<dim3(256, 16), 256, 0, stream>>>(
      a_raw_p, bih_raw_p, nullptr, xg_raw_p, rf_b, rb_b, KP, 0, (size_t)32*1024*1024);
  gemm_kernel<1><<<dim3(32, 16), 256, 0, stream>>>(
      a_sum_p, bih_sum_p, nullptr, xg_sum_p, sf_b, sb_b, KP, 0, (size_t)32*128*1024);

  lstm_kernel<<<128, 256, 0, stream>>>(whh16_p, xg_raw_p, xg_sum_p, out_raw_p, out_sum_p);

  gemm_kernel<0><<<dim3(256, 4), 256, 0, stream>>>(
      out_raw_p, wq16_p, qout, nullptr, nullptr, nullptr, 512, 512, 0);

  pool_kv_kernel<<<32, 256, 0, stream>>>(out_sum_p, len_sum, wk, wv, kb_p, vb_p);
  attn_kernel<<<128, 256, 0, stream>>>(qout, kb_p, attn_p);
  final_kernel<<<4096, 256, 0, stream>>>(qout, attn_p, vb_p);
}

// Round 10
// 2449.223 us; speedup vs baseline: 2.9784x; 1.2639x over previous
//
#include <hip/hip_runtime.h>

typedef _Float16 f16;
typedef _Float16 half2t __attribute__((ext_vector_type(2)));
typedef _Float16 half8 __attribute__((ext_vector_type(8)));
typedef float f32x4 __attribute__((ext_vector_type(4)));

#define KP 320
#define DIN 300
#define SRAW 1024
#define SSUM 128

// ---------------- workspace layout (bytes) ----------------
static constexpr size_t OFF_XG_RAW  = 0;                                        // f16 [2][32][1024][1024] natural gate-major
static constexpr size_t OFF_XG_SUM  = OFF_XG_RAW + (size_t)2*32*1024*1024*2;    // f16 [2][32][128][1024]
static constexpr size_t OFF_OUT_RAW = OFF_XG_SUM + (size_t)2*32*128*1024*2;     // f16 [32][1024][512]
static constexpr size_t OFF_OUT_SUM = OFF_OUT_RAW + (size_t)32*1024*512*2;      // f16 [32][128][512]
static constexpr size_t OFF_A_RAW   = OFF_OUT_SUM + (size_t)32*128*512*2;       // f16 [32768][320]
static constexpr size_t OFF_A_SUM   = OFF_A_RAW + (size_t)32768*KP*2;           // f16 [4096][320]
static constexpr size_t OFF_BIH_RAW = OFF_A_SUM + (size_t)4096*KP*2;            // f16 [2048][320]
static constexpr size_t OFF_BIH_SUM = OFF_BIH_RAW + (size_t)2048*KP*2;          // f16 [2048][320]
static constexpr size_t OFF_WHH     = OFF_BIH_SUM + (size_t)2048*KP*2;          // f16 [4][8][4][16][64][8] (uint4 chunks)
static constexpr size_t OFF_WQ      = OFF_WHH + (size_t)4*8*4*16*64*8*2;        // f16 [512][512]
static constexpr size_t OFF_KB      = OFF_WQ + (size_t)512*512*2;               // f32 [4][32][128]
static constexpr size_t OFF_VB      = OFF_KB + (size_t)4*32*128*4;              // f32 [4][32][128]
static constexpr size_t OFF_ATTN    = OFF_VB + (size_t)4*32*128*4;              // f32 [4][32][1024]
static constexpr size_t WS_NEED     = OFF_ATTN + (size_t)4*32*1024*4;           // ~208 MB

// ---------------- pack / convert ----------------
// Whh layout per (ed): [w(8)][m(4)][c(16)][l(64)] uint4 (8 f16 each).
// wave w = (rb=w>>1, kh=w&1); thread lane l owns rows rb*256 + l + 64m over
// k = kh*128 + c*8 + ii.
__global__ void pack_kernel(
    const float* __restrict__ in_raw, const float* __restrict__ in_sum,
    const float* __restrict__ wih_rf, const float* __restrict__ wih_rb,
    const float* __restrict__ wih_sf, const float* __restrict__ wih_sb,
    const float* __restrict__ whh_rf, const float* __restrict__ whh_rb,
    const float* __restrict__ whh_sf, const float* __restrict__ whh_sb,
    const float* __restrict__ wq,
    f16* __restrict__ a_raw, f16* __restrict__ a_sum,
    f16* __restrict__ bih_raw, f16* __restrict__ bih_sum,
    f16* __restrict__ whh16, f16* __restrict__ wq16)
{
  constexpr size_t N1 = (size_t)32768*KP;
  constexpr size_t N2 = (size_t)4096*KP;
  constexpr size_t N3 = (size_t)2048*KP;
  constexpr size_t N5 = (size_t)4*8*4*16*64*8;    // 1048576 f16
  constexpr size_t N6 = (size_t)512*512;
  const size_t TOT = N1+N2+N3+N3+N5+N6;
  const size_t stride = (size_t)gridDim.x*blockDim.x;
  for (size_t i = (size_t)blockIdx.x*blockDim.x + threadIdx.x; i < TOT; i += stride) {
    size_t j = i;
    if (j < N1) {
      size_t m = j/KP, k = j - m*KP;
      a_raw[j] = (f16)(k < DIN ? in_raw[m*DIN + k] : 0.f);
      continue;
    }
    j -= N1;
    if (j < N2) {
      size_t m = j/KP, k = j - m*KP;
      a_sum[j] = (f16)(k < DIN ? in_sum[m*DIN + k] : 0.f);
      continue;
    }
    j -= N2;
    if (j < N3) {
      size_t n = j/KP, k = j - n*KP;
      float v = 0.f;
      if (k < DIN) v = (n < 1024) ? wih_rf[n*DIN + k] : wih_rb[(n-1024)*DIN + k];
      bih_raw[j] = (f16)v;
      continue;
    }
    j -= N3;
    if (j < N3) {
      size_t n = j/KP, k = j - n*KP;
      float v = 0.f;
      if (k < DIN) v = (n < 1024) ? wih_sf[n*DIN + k] : wih_sb[(n-1024)*DIN + k];
      bih_sum[j] = (f16)v;
      continue;
    }
    j -= N3;
    if (j < N5) {
      int ed = (int)(j >> 18);                 // 262144 f16 per ed
      int q  = (int)((j >> 3) & 32767);        // uint4 index within ed
      int ii = (int)(j & 7);
      int l  = q & 63;
      int c  = (q >> 6) & 15;
      int m  = (q >> 10) & 3;
      int w  = (q >> 12) & 7;
      int rb = w >> 1, kh = w & 1;
      int row = rb*256 + l + 64*m;
      int col = kh*128 + c*8 + ii;
      const float* src = (ed==0)?whh_rf:(ed==1)?whh_rb:(ed==2)?whh_sf:whh_sb;
      whh16[j] = (f16)src[(size_t)row*256 + col];
      continue;
    }
    j -= N5;
    {
      int n = (int)(j >> 9), k = (int)(j & 511);
      int h = n >> 7, dh = n & 127;
      wq16[j] = (f16)wq[((size_t)h*512 + k)*128 + dh];
    }
  }
}

// ---------------- f16 MFMA GEMM: C[M,N] = A[M,K] * B[N,K]^T ----------------
template<int EPI>
__global__ __launch_bounds__(256) void gemm_kernel(
    const f16* __restrict__ A, const f16* __restrict__ Bm,
    float* __restrict__ Cf, f16* __restrict__ Cx,
    const float* __restrict__ bias0, const float* __restrict__ bias1,
    int K, int ldcN, size_t dirStride)
{
  __shared__ __align__(16) f16 As[128*40];
  __shared__ __align__(16) f16 Bs[128*40];
  const int tid = threadIdx.x;
  const int m0 = blockIdx.x*128, n0 = blockIdx.y*128;
  const int w = tid >> 6, lane = tid & 63;
  const int wm = w >> 1, wn = w & 1;
  const int lr = lane & 15, lk = lane >> 4;
  f32x4 acc[4][4] = {};
  const int nsteps = K >> 5;
  for (int kt = 0; kt < nsteps; ++kt) {
    __syncthreads();
    #pragma unroll
    for (int it = 0; it < 2; ++it) {
      int c = tid + it*256;
      int r = c >> 2, kc = c & 3;
      *(uint4*)&As[r*40 + kc*8] = *(const uint4*)&A[(size_t)(m0+r)*K + kt*32 + kc*8];
      *(uint4*)&Bs[r*40 + kc*8] = *(const uint4*)&Bm[(size_t)(n0+r)*K + kt*32 + kc*8];
    }
    __syncthreads();
    half8 af[4], bf[4];
    #pragma unroll
    for (int mt = 0; mt < 4; ++mt) af[mt] = *(const half8*)&As[(wm*64 + mt*16 + lr)*40 + lk*8];
    #pragma unroll
    for (int nt = 0; nt < 4; ++nt) bf[nt] = *(const half8*)&Bs[(wn*64 + nt*16 + lr)*40 + lk*8];
    #pragma unroll
    for (int mt = 0; mt < 4; ++mt)
      #pragma unroll
      for (int nt = 0; nt < 4; ++nt)
        acc[mt][nt] = __builtin_amdgcn_mfma_f32_16x16x32_f16(af[mt], bf[nt], acc[mt][nt], 0, 0, 0);
  }
  const int rb = lk*4;
  #pragma unroll
  for (int mt = 0; mt < 4; ++mt) {
    #pragma unroll
    for (int nt = 0; nt < 4; ++nt) {
      int n = n0 + wn*64 + nt*16 + lr;
      int mloc = m0 + wm*64 + mt*16 + rb;
      if (EPI == 0) {
        #pragma unroll
        for (int r = 0; r < 4; ++r)
          Cf[(size_t)(mloc+r)*ldcN + n] = acc[mt][nt][r];
      } else {
        int dir = n >> 10, cc = n & 1023;
        float bs = (dir ? bias1 : bias0)[cc];
        f16* dst = Cx + (size_t)dir*dirStride;
        #pragma unroll
        for (int r = 0; r < 4; ++r)
          dst[(size_t)(mloc+r)*1024 + cc] = (f16)(acc[mt][nt][r] + bs);
      }
    }
  }
}

// ---------------- LSTM recurrence: scalar-h (SGPR broadcast) ----------------
// 1 WG (512 thr, 8 waves) per (e,d,b). Wave w: kh=w&1 (k-half), rb=w>>1 (gate
// block). Thread lane l owns rows rb*256+l+64m over its k-half:
//   m=0..2 from registers (192 dw, pinned), m=3 from LDS (128 KB).
// h's k-half enters via 1 ds_read_b32 + v_readlane -> SGPRs; v_dot2_f32_f16
// takes h as the SGPR operand (inline asm "s" constraint) -> no LDS h
// broadcasts, no DPP reduce, no selects. kh-half partials exchanged via LDS.

__device__ __forceinline__ float sdot2(float acc, unsigned w2, int h2) {
  asm("v_dot2_f32_f16 %0, %1, %2, %0" : "+v"(acc) : "v"(w2), "s"(h2));
  return acc;
}

__device__ __forceinline__ float sigmoid_f(float x) {
  float e = __expf(-x);
  return __builtin_amdgcn_rcpf(1.f + e);
}
__device__ __forceinline__ float tanh_f(float x) {
  float e = __expf(2.f * x);
  return 1.f - 2.f * __builtin_amdgcn_rcpf(e + 1.f);
}

__device__ __forceinline__ void pin4(uint4& v) {
  asm volatile("" : "+v"(v.x), "+v"(v.y), "+v"(v.z), "+v"(v.w));
}

__global__ void __launch_bounds__(512, 2)
lstm_kernel(
    const f16* __restrict__ whh16,
    const f16* __restrict__ xg_raw, const f16* __restrict__ xg_sum,
    f16* __restrict__ out_raw, f16* __restrict__ out_sum)
{
  const int wg = blockIdx.x;               // [e(1)][d(1)][b(5)]
  const int e = wg >> 6, d = (wg >> 5) & 1, b = wg & 31;
  const int S = e ? SSUM : SRAW;
  const int t = threadIdx.x;
  const int l = t & 63, w = t >> 6;
  const int kh = w & 1, rb = w >> 1;
  const uint4* wb = (const uint4*)whh16 + (size_t)(e*2+d)*32768 + (size_t)w*4096 + l;
  const f16* xg = (e ? xg_sum : xg_raw) + ((size_t)(d*32 + b))*(size_t)S*1024;
  f16* outp = (e ? out_sum : out_raw) + (size_t)b*S*512 + d*256;

  __shared__ __align__(16) uint4 wl[16*512];   // 128 KB: m=3 row-halves
  __shared__ float pp[1024];                    // kh=1 partials
  __shared__ float actL[1024];                  // activated gate values
  __shared__ __align__(8) f16 hl[256];          // h state

  // stage m=3 row-half into LDS (thread reads back its own slot)
  #pragma unroll
  for (int c = 0; c < 16; ++c) wl[c*512 + t] = wb[(size_t)(3*16 + c)*64];
  // register rows m=0..2 (48 uint4 = 192 dw), pinned against sinking
  uint4 wr[48];
  #pragma unroll
  for (int k = 0; k < 48; ++k) wr[k] = wb[(size_t)k*64];
  #pragma unroll
  for (int k = 0; k < 48; ++k) pin4(wr[k]);

  if (t < 256) hl[t] = (f16)0.f;
  float cst = 0.f;
  const int row0 = rb*256 + l;                 // rows row0 + 64m
  const bool isG = (rb == 2);
  __syncthreads();

  for (int st = 0; st < S; ++st) {
    const int s = d ? (S - 1 - st) : st;

    // xg terms for this step (kh==0 waves only; coalesced 2B xl loads)
    float xv0 = 0.f, xv1 = 0.f, xv2 = 0.f, xv3 = 0.f;
    if (kh == 0) {
      xv0 = (float)xg[(size_t)s*1024 + row0];
      xv1 = (float)xg[(size_t)s*1024 + row0 + 64];
      xv2 = (float)xg[(size_t)s*1024 + row0 + 128];
      xv3 = (float)xg[(size_t)s*1024 + row0 + 192];
    }

    // own k-half of h: one dw per lane, then readlane -> SGPR broadcast
    int hdw = ((const int*)hl)[kh*64 + l];

    float acc0 = 0.f, acc1 = 0.f, acc2 = 0.f, acc3 = 0.f;
    #pragma unroll
    for (int c = 0; c < 16; ++c) {
      uint4 wv3 = wl[c*512 + t];               // LDS row (static addr, pipelines)
      int h0 = __builtin_amdgcn_readlane(hdw, c*4 + 0);
      int h1 = __builtin_amdgcn_readlane(hdw, c*4 + 1);
      int h2 = __builtin_amdgcn_readlane(hdw, c*4 + 2);
      int h3 = __builtin_amdgcn_readlane(hdw, c*4 + 3);
      uint4 w0 = wr[c], w1 = wr[16 + c], w2 = wr[32 + c];
      acc0 = sdot2(acc0, w0.x, h0); acc0 = sdot2(acc0, w0.y, h1);
      acc0 = sdot2(acc0, w0.z, h2); acc0 = sdot2(acc0, w0.w, h3);
      acc1 = sdot2(acc1, w1.x, h0); acc1 = sdot2(acc1, w1.y, h1);
      acc1 = sdot2(acc1, w1.z, h2); acc1 = sdot2(acc1, w1.w, h3);
      acc2 = sdot2(acc2, w2.x, h0); acc2 = sdot2(acc2, w2.y, h1);
      acc2 = sdot2(acc2, w2.z, h2); acc2 = sdot2(acc2, w2.w, h3);
      acc3 = sdot2(acc3, wv3.x, h0); acc3 = sdot2(acc3, wv3.y, h1);
      acc3 = sdot2(acc3, wv3.z, h2); acc3 = sdot2(acc3, wv3.w, h3);
    }

    if (kh == 1) {                             // publish k-high partials
      pp[row0]       = acc0;
      pp[row0 + 64]  = acc1;
      pp[row0 + 128] = acc2;
      pp[row0 + 192] = acc3;
    }
    __syncthreads();

    if (kh == 0) {                             // sum halves + activate (uniform type)
      float t0 = acc0 + pp[row0]       + xv0;
      float t1 = acc1 + pp[row0 + 64]  + xv1;
      float t2 = acc2 + pp[row0 + 128] + xv2;
      float t3 = acc3 + pp[row0 + 192] + xv3;
      actL[row0]       = isG ? tanh_f(t0) : sigmoid_f(t0);
      actL[row0 + 64]  = isG ? tanh_f(t1) : sigmoid_f(t1);
      actL[row0 + 128] = isG ? tanh_f(t2) : sigmoid_f(t2);
      actL[row0 + 192] = isG ? tanh_f(t3) : sigmoid_f(t3);
    }
    __syncthreads();

    if (t < 256) {                             // tail: unit t
      float ig = actL[t], fg = actL[256 + t], gg = actL[512 + t], og = actL[768 + t];
      cst = fg*cst + ig*gg;
      float hval = og*tanh_f(cst);
      f16 hf = (f16)hval;
      hl[t] = hf;
      outp[(size_t)s*512 + t] = hf;
    }
    __syncthreads();
  }
}

// ---------------- mean pool + k,v projection ----------------
__global__ __launch_bounds__(256) void pool_kv_kernel(
    const f16* __restrict__ out_sum, const int* __restrict__ len_sum,
    const float* __restrict__ Wk, const float* __restrict__ Wv,
    float* __restrict__ kb, float* __restrict__ vb)
{
  const int b = blockIdx.x, t = threadIdx.x;
  __shared__ float sv[512];
  int len = len_sum[b]; if (len < 1) len = 1;
  float a0 = 0.f, a1 = 0.f;
  for (int s = 0; s < len; ++s) {
    const f16* row = out_sum + ((size_t)b*SSUM + s)*512;
    a0 += (float)row[t];
    a1 += (float)row[t+256];
  }
  float inv = 1.f/(float)len;
  sv[t] = a0*inv; sv[t+256] = a1*inv;
  __syncthreads();
  #pragma unroll
  for (int half = 0; half < 2; ++half) {
    int o = t + half*256;
    int h = o >> 7, dh = o & 127;
    const float* wkp = Wk + (size_t)h*512*128 + dh;
    const float* wvp = Wv + (size_t)h*512*128 + dh;
    float ak = 0.f, av = 0.f;
    for (int e2 = 0; e2 < 512; ++e2) {
      float sve = sv[e2];
      ak += sve*wkp[(size_t)e2*128];
      av += sve*wvp[(size_t)e2*128];
    }
    kb[((size_t)h*32 + b)*128 + dh] = ak;
    vb[((size_t)h*32 + b)*128 + dh] = av;
  }
}

// ---------------- scores + softmax ----------------
__global__ __launch_bounds__(256) void attn_kernel(
    const float* __restrict__ q, const float* __restrict__ kb, float* __restrict__ attn)
{
  const int hb = blockIdx.x;          // h*32 + b
  const int h = hb >> 5, b = hb & 31;
  const int t = threadIdx.x;
  __shared__ __align__(16) float kk[128];
  __shared__ float red[4];
  if (t < 128) kk[t] = kb[(size_t)hb*128 + t];
  __syncthreads();
  float vals[4];
  #pragma unroll
  for (int i = 0; i < 4; ++i) {
    int s = t + i*256;
    const float4* qp = (const float4*)(q + ((size_t)b*1024 + s)*512 + h*128);
    const float4* kp = (const float4*)kk;
    float a = 0.f;
    #pragma unroll
    for (int e2 = 0; e2 < 32; ++e2) {
      float4 qq = qp[e2], kx = kp[e2];
      a += qq.x*kx.x + qq.y*kx.y + qq.z*kx.z + qq.w*kx.w;
    }
    vals[i] = a;
  }
  float m = fmaxf(fmaxf(vals[0], vals[1]), fmaxf(vals[2], vals[3]));
  for (int o = 1; o < 64; o <<= 1) m = fmaxf(m, __shfl_xor(m, o));
  if ((t & 63) == 0) red[t >> 6] = m;
  __syncthreads();
  m = fmaxf(fmaxf(red[0], red[1]), fmaxf(red[2], red[3]));
  __syncthreads();
  float ex[4], lsum = 0.f;
  #pragma unroll
  for (int i = 0; i < 4; ++i) { ex[i] = __expf(vals[i] - m); lsum += ex[i]; }
  for (int o = 1; o < 64; o <<= 1) lsum += __shfl_xor(lsum, o);
  if ((t & 63) == 0) red[t >> 6] = lsum;
  __syncthreads();
  float inv = 1.f/(red[0] + red[1] + red[2] + red[3]);
  #pragma unroll
  for (int i = 0; i < 4; ++i) attn[(size_t)hb*1024 + t + i*256] = ex[i]*inv;
}

// ---------------- final: out = q + attn * v ----------------
__global__ __launch_bounds__(256) void final_kernel(
    float* __restrict__ out, const float* __restrict__ attn, const float* __restrict__ vb)
{
  const size_t TOT4 = (size_t)32*1024*512/4;
  const size_t stride = (size_t)gridDim.x*blockDim.x;
  for (size_t i = (size_t)blockIdx.x*blockDim.x + threadIdx.x; i < TOT4; i += stride) {
    int c4 = (int)(i & 127);
    int h = c4 >> 5;
    size_t srow = i >> 7;
    int b = (int)(srow >> 10), s = (int)(srow & 1023);
    float a = attn[((size_t)h*32 + b)*1024 + s];
    float4 vv = ((const float4*)vb)[((size_t)h*32 + b)*32 + (c4 & 31)];
    float4 qq = ((float4*)out)[i];
    qq.x += a*vv.x; qq.y += a*vv.y; qq.z += a*vv.z; qq.w += a*vv.w;
    ((float4*)out)[i] = qq;
  }
}

// ---------------- launch ----------------
extern "C" void kernel_launch(void* const* d_in, const int* in_sizes, int n_in,
                              void* d_out, int out_size, void* d_ws, size_t ws_size,
                              hipStream_t stream)
{
  const float* in_raw = (const float*)d_in[0];
  const float* in_sum = (const float*)d_in[1];
  const int*  len_sum = (const int*)d_in[3];
  const float* rf_wih = (const float*)d_in[4];
  const float* rf_whh = (const float*)d_in[5];
  const float* rf_b   = (const float*)d_in[6];
  const float* rb_wih = (const float*)d_in[7];
  const float* rb_whh = (const float*)d_in[8];
  const float* rb_b   = (const float*)d_in[9];
  const float* sf_wih = (const float*)d_in[10];
  const float* sf_whh = (const float*)d_in[11];
  const float* sf_b   = (const float*)d_in[12];
  const float* sb_wih = (const float*)d_in[13];
  const float* sb_whh = (const float*)d_in[14];
  const float* sb_b   = (const float*)d_in[15];
  const float* wq     = (const float*)d_in[16];
  const float* wk     = (const float*)d_in[17];
  const float* wv     = (const float*)d_in[18];

  if (ws_size < WS_NEED) return;

  char* ws = (char*)d_ws;
  f16* xg_raw_p  = (f16*)(ws + OFF_XG_RAW);
  f16* xg_sum_p  = (f16*)(ws + OFF_XG_SUM);
  f16* out_raw_p = (f16*)(ws + OFF_OUT_RAW);
  f16* out_sum_p = (f16*)(ws + OFF_OUT_SUM);
  f16* a_raw_p   = (f16*)(ws + OFF_A_RAW);
  f16* a_sum_p   = (f16*)(ws + OFF_A_SUM);
  f16* bih_raw_p = (f16*)(ws + OFF_BIH_RAW);
  f16* bih_sum_p = (f16*)(ws + OFF_BIH_SUM);
  f16* whh16_p   = (f16*)(ws + OFF_WHH);
  f16* wq16_p    = (f16*)(ws + OFF_WQ);
  float* kb_p    = (float*)(ws + OFF_KB);
  float* vb_p    = (float*)(ws + OFF_VB);
  float* attn_p  = (float*)(ws + OFF_ATTN);
  float* qout    = (float*)d_out;

  pack_kernel<<<4096, 256, 0, stream>>>(
      in_raw, in_sum, rf_wih, rb_wih, sf_wih, sb_wih,
      rf_whh, rb_whh, sf_whh, sb_whh, wq,
      a_raw_p, a_sum_p, bih_raw_p, bih_sum_p, whh16_p, wq16_p);

  gemm_kernel<1><<<dim3(256, 16), 256, 0, stream>>>(
      a_raw_p, bih_raw_p, nullptr, xg_raw_p, rf_b, rb_b, KP, 0, (size_t)32*1024*1024);
  gemm_kernel<1><<<dim3(32, 16), 256, 0, stream>>>(
      a_sum_p, bih_sum_p, nullptr, xg_sum_p, sf_b, sb_b, KP, 0, (size_t)32*128*1024);

  lstm_kernel<<<128, 512, 0, stream>>>(whh16_p, xg_raw_p, xg_sum_p, out_raw_p, out_sum_p);

  gemm_kernel<0><<<dim3(256, 4), 256, 0, stream>>>(
      out_raw_p, wq16_p, qout, nullptr, nullptr, nullptr, 512, 512, 0);

  pool_kv_kernel<<<32, 256, 0, stream>>>(out_sum_p, len_sum, wk, wv, kb_p, vb_p);
  attn_kernel<<<128, 256, 0, stream>>>(qout, kb_p, attn_p);
  final_kernel<<<4096, 256, 0, stream>>>(qout, attn_p, vb_p);
}

// Round 11
// 2204.367 us; speedup vs baseline: 3.3092x; 1.1111x over previous
//
#include <hip/hip_runtime.h>

typedef _Float16 f16;
typedef _Float16 half2t __attribute__((ext_vector_type(2)));
typedef _Float16 half8 __attribute__((ext_vector_type(8)));
typedef float f32x4 __attribute__((ext_vector_type(4)));

#define KP 320
#define DIN 300
#define SRAW 1024
#define SSUM 128

// ---------------- workspace layout (bytes) ----------------
static constexpr size_t OFF_XG_RAW  = 0;                                        // f16 [2][32][1024][1024] natural gate-major
static constexpr size_t OFF_XG_SUM  = OFF_XG_RAW + (size_t)2*32*1024*1024*2;    // f16 [2][32][128][1024]
static constexpr size_t OFF_OUT_RAW = OFF_XG_SUM + (size_t)2*32*128*1024*2;     // f16 [32][1024][512]
static constexpr size_t OFF_OUT_SUM = OFF_OUT_RAW + (size_t)32*1024*512*2;      // f16 [32][128][512]
static constexpr size_t OFF_A_RAW   = OFF_OUT_SUM + (size_t)32*128*512*2;       // f16 [32768][320]
static constexpr size_t OFF_A_SUM   = OFF_A_RAW + (size_t)32768*KP*2;           // f16 [4096][320]
static constexpr size_t OFF_BIH_RAW = OFF_A_SUM + (size_t)4096*KP*2;            // f16 [2048][320]
static constexpr size_t OFF_BIH_SUM = OFF_BIH_RAW + (size_t)2048*KP*2;          // f16 [2048][320]
static constexpr size_t OFF_WHH     = OFF_BIH_SUM + (size_t)2048*KP*2;          // f16 [4][64][512][8] chunk layout
static constexpr size_t OFF_WQ      = OFF_WHH + (size_t)4*64*512*8*2;           // f16 [512][512]
static constexpr size_t OFF_KB      = OFF_WQ + (size_t)512*512*2;               // f32 [4][32][128]
static constexpr size_t OFF_VB      = OFF_KB + (size_t)4*32*128*4;              // f32 [4][32][128]
static constexpr size_t OFF_ATTN    = OFF_VB + (size_t)4*32*128*4;              // f32 [4][32][1024]
static constexpr size_t WS_NEED     = OFF_ATTN + (size_t)4*32*1024*4;           // ~208 MB

// ---------------- pack / convert ----------------
// Whh chunk layout: [ed][c(64)][t(512)][8 f16], where for thread t (rg=t>>3, ks=t&7)
// chunk c = j*4+q holds W[rg*16+j][ks*32+q*8 .. +8)  -- j in [0,16), q in [0,4)
__global__ void pack_kernel(
    const float* __restrict__ in_raw, const float* __restrict__ in_sum,
    const float* __restrict__ wih_rf, const float* __restrict__ wih_rb,
    const float* __restrict__ wih_sf, const float* __restrict__ wih_sb,
    const float* __restrict__ whh_rf, const float* __restrict__ whh_rb,
    const float* __restrict__ whh_sf, const float* __restrict__ whh_sb,
    const float* __restrict__ wq,
    f16* __restrict__ a_raw, f16* __restrict__ a_sum,
    f16* __restrict__ bih_raw, f16* __restrict__ bih_sum,
    f16* __restrict__ whh16, f16* __restrict__ wq16)
{
  constexpr size_t N1 = (size_t)32768*KP;
  constexpr size_t N2 = (size_t)4096*KP;
  constexpr size_t N3 = (size_t)2048*KP;
  constexpr size_t N5 = (size_t)4*64*512*8;
  constexpr size_t N6 = (size_t)512*512;
  const size_t TOT = N1+N2+N3+N3+N5+N6;
  const size_t stride = (size_t)gridDim.x*blockDim.x;
  for (size_t i = (size_t)blockIdx.x*blockDim.x + threadIdx.x; i < TOT; i += stride) {
    size_t j = i;
    if (j < N1) {
      size_t m = j/KP, k = j - m*KP;
      a_raw[j] = (f16)(k < DIN ? in_raw[m*DIN + k] : 0.f);
      continue;
    }
    j -= N1;
    if (j < N2) {
      size_t m = j/KP, k = j - m*KP;
      a_sum[j] = (f16)(k < DIN ? in_sum[m*DIN + k] : 0.f);
      continue;
    }
    j -= N2;
    if (j < N3) {
      size_t n = j/KP, k = j - n*KP;
      float v = 0.f;
      if (k < DIN) v = (n < 1024) ? wih_rf[n*DIN + k] : wih_rb[(n-1024)*DIN + k];
      bih_raw[j] = (f16)v;
      continue;
    }
    j -= N3;
    if (j < N3) {
      size_t n = j/KP, k = j - n*KP;
      float v = 0.f;
      if (k < DIN) v = (n < 1024) ? wih_sf[n*DIN + k] : wih_sb[(n-1024)*DIN + k];
      bih_sum[j] = (f16)v;
      continue;
    }
    j -= N3;
    if (j < N5) {
      int ed = (int)(j >> 18);
      int c  = (int)((j >> 12) & 63);
      int t  = (int)((j >> 3) & 511);
      int ii = (int)(j & 7);
      int jrow = c >> 2, q = c & 3;
      int rg = t >> 3, ks = t & 7;
      int row = rg*16 + jrow;
      int col = ks*32 + q*8 + ii;
      const float* src = (ed==0)?whh_rf:(ed==1)?whh_rb:(ed==2)?whh_sf:whh_sb;
      whh16[j] = (f16)src[(size_t)row*256 + col];
      continue;
    }
    j -= N5;
    {
      int n = (int)(j >> 9), k = (int)(j & 511);
      int h = n >> 7, dh = n & 127;
      wq16[j] = (f16)wq[((size_t)h*512 + k)*128 + dh];
    }
  }
}

// ---------------- f16 MFMA GEMM: C[M,N] = A[M,K] * B[N,K]^T ----------------
// EPI 0: plain f32 store.  EPI 1: +bias, f16 store split by dir, natural layout.
template<int EPI>
__global__ __launch_bounds__(256) void gemm_kernel(
    const f16* __restrict__ A, const f16* __restrict__ Bm,
    float* __restrict__ Cf, f16* __restrict__ Cx,
    const float* __restrict__ bias0, const float* __restrict__ bias1,
    int K, int ldcN, size_t dirStride)
{
  __shared__ __align__(16) f16 As[128*40];
  __shared__ __align__(16) f16 Bs[128*40];
  const int tid = threadIdx.x;
  const int m0 = blockIdx.x*128, n0 = blockIdx.y*128;
  const int w = tid >> 6, lane = tid & 63;
  const int wm = w >> 1, wn = w & 1;
  const int lr = lane & 15, lk = lane >> 4;
  f32x4 acc[4][4] = {};
  const int nsteps = K >> 5;
  for (int kt = 0; kt < nsteps; ++kt) {
    __syncthreads();
    #pragma unroll
    for (int it = 0; it < 2; ++it) {
      int c = tid + it*256;
      int r = c >> 2, kc = c & 3;
      *(uint4*)&As[r*40 + kc*8] = *(const uint4*)&A[(size_t)(m0+r)*K + kt*32 + kc*8];
      *(uint4*)&Bs[r*40 + kc*8] = *(const uint4*)&Bm[(size_t)(n0+r)*K + kt*32 + kc*8];
    }
    __syncthreads();
    half8 af[4], bf[4];
    #pragma unroll
    for (int mt = 0; mt < 4; ++mt) af[mt] = *(const half8*)&As[(wm*64 + mt*16 + lr)*40 + lk*8];
    #pragma unroll
    for (int nt = 0; nt < 4; ++nt) bf[nt] = *(const half8*)&Bs[(wn*64 + nt*16 + lr)*40 + lk*8];
    #pragma unroll
    for (int mt = 0; mt < 4; ++mt)
      #pragma unroll
      for (int nt = 0; nt < 4; ++nt)
        acc[mt][nt] = __builtin_amdgcn_mfma_f32_16x16x32_f16(af[mt], bf[nt], acc[mt][nt], 0, 0, 0);
  }
  const int rb = lk*4;
  #pragma unroll
  for (int mt = 0; mt < 4; ++mt) {
    #pragma unroll
    for (int nt = 0; nt < 4; ++nt) {
      int n = n0 + wn*64 + nt*16 + lr;
      int mloc = m0 + wm*64 + mt*16 + rb;
      if (EPI == 0) {
        #pragma unroll
        for (int r = 0; r < 4; ++r)
          Cf[(size_t)(mloc+r)*ldcN + n] = acc[mt][nt][r];
      } else {
        int dir = n >> 10, cc = n & 1023;
        float bs = (dir ? bias1 : bias0)[cc];
        f16* dst = Cx + (size_t)dir*dirStride;
        #pragma unroll
        for (int r = 0; r < 4; ++r)
          dst[(size_t)(mloc+r)*1024 + cc] = (f16)(acc[mt][nt][r] + bs);
      }
    }
  }
}

// ---------------- LSTM recurrence (lane k-sliced) ----------------
// 1 WG (512 threads) per (e,d,b). Thread t: rg=t>>3 (row group), ks=t&7 (k-slice
// of 32). Rows r = rg*16+j, j=0..15: j<14 register-resident (224 dw, pinned),
// j=14..15 read from LDS each step (64 KB). No L2 weight streams.
// Distributed activations: gate = t>>7 is WAVE-uniform -> scalar branch, one
// exp-chain side; tail is 4 LDS reads + fma + tanh + stores.
#define RROWS 14
#define LROWS 2

__device__ __forceinline__ float dot8(float acc, uint4 wv, uint4 hv) {
#if __has_builtin(__builtin_amdgcn_fdot2)
  union { uint4 u; half2t h[4]; } W, Hh;
  W.u = wv; Hh.u = hv;
  #pragma unroll
  for (int i = 0; i < 4; ++i) acc = __builtin_amdgcn_fdot2(W.h[i], Hh.h[i], acc, false);
#else
  union { uint4 u; f16 h[8]; } W, Hh;
  W.u = wv; Hh.u = hv;
  #pragma unroll
  for (int i = 0; i < 8; ++i) acc += (float)W.h[i]*(float)Hh.h[i];
#endif
  return acc;
}

__device__ __forceinline__ float sigmoid_f(float x) {
  float e = __expf(-x);
  return __builtin_amdgcn_rcpf(1.f + e);
}
__device__ __forceinline__ float tanh_f(float x) {
  float e = __expf(2.f * x);
  return 1.f - 2.f * __builtin_amdgcn_rcpf(e + 1.f);
}

__device__ __forceinline__ void pin4(uint4& v) {
  asm volatile("" : "+v"(v.x), "+v"(v.y), "+v"(v.z), "+v"(v.w));
}

// DPP butterfly add over the 8-lane k-slice group (VALU pipe, no LDS).
template<int CTRL>
__device__ __forceinline__ float dpp_add(float v) {
  int m = __builtin_amdgcn_update_dpp(0, __builtin_bit_cast(int, v), CTRL, 0xf, 0xf, true);
  return v + __builtin_bit_cast(float, m);
}
__device__ __forceinline__ float reduce8(float v) {
  v = dpp_add<0xB1>(v);   // quad_perm [1,0,3,2]  : lane ^ 1
  v = dpp_add<0x4E>(v);   // quad_perm [2,3,0,1]  : lane ^ 2
  v = dpp_add<0x141>(v);  // row_half_mirror      : cross 4-group within 8
  return v;
}

__global__ void __launch_bounds__(512, 2) __attribute__((amdgpu_waves_per_eu(2, 2)))
lstm_kernel(
    const f16* __restrict__ whh16,
    const f16* __restrict__ xg_raw, const f16* __restrict__ xg_sum,
    f16* __restrict__ out_raw, f16* __restrict__ out_sum)
{
  const int wg = blockIdx.x;               // [e(1)][d(1)][b(5)]
  const int e = wg >> 6, r2 = wg & 63, d = r2 >> 5, b = r2 & 31;
  const int S = e ? SSUM : SRAW;
  const int t = threadIdx.x;
  const int rg = t >> 3, ks = t & 7;
  const uint4* wb = (const uint4*)(whh16 + (size_t)(e*2+d)*(64*512*8));
  const f16* xg = (e ? xg_sum : xg_raw) + ((size_t)(d*32 + b))*(size_t)S*1024;
  f16* outp = (e ? out_sum : out_raw) + (size_t)b*S*512 + d*256;

  __shared__ __align__(16) uint4 wl[LROWS*4*512];   // 64 KB: rows 14,15
  __shared__ float pre[1024];                        // ACTIVATED gate values
  __shared__ __align__(16) f16 hrep[4*264];          // 4 padded copies of h[256]

  // stage LDS weight rows (chunks 56..63)
  #pragma unroll
  for (int c = 0; c < LROWS*4; ++c) wl[c*512 + t] = wb[(RROWS*4 + c)*512 + t];
  // register weight rows 0..13 (chunks 0..55), pinned against rematerialization
  uint4 wr[RROWS*4];
  #pragma unroll
  for (int c = 0; c < RROWS*4; ++c) wr[c] = wb[c*512 + t];
  #pragma unroll
  for (int c = 0; c < RROWS*4; ++c) pin4(wr[c]);

  if (t < 256) {
    #pragma unroll
    for (int cpy = 0; cpy < 4; ++cpy) hrep[cpy*264 + t] = (f16)0.f;
  }
  float cst = 0.f;
  const int hbyte = (ks >> 1)*528 + ks*64;               // conflict-free slice base
  const int gate = rg >> 4;                              // wave-uniform (t>>7)
  const int preS = (gate << 8) + ((rg & 15) << 4);       // gate*256 + unit-base
  const int ua = (gate << 8) + ((rg & 15) << 4) + ks;    // natural xg index, row A
  const bool isG = (gate == 2);
  __syncthreads();

  for (int st = 0; st < S; ++st) {
    const int s = d ? (S - 1 - st) : st;

    // xg terms for this thread's two rows (natural gate-major layout);
    // issued at loop top, consumed ~full dot phase later.
    float xva = (float)xg[(size_t)s*1024 + ua];
    float xvb = (float)xg[(size_t)s*1024 + ua + 8];

    // h slice (32 elems) from replicated copy — conflict-free
    uint4 hv[4];
    #pragma unroll
    for (int q = 0; q < 4; ++q)
      hv[q] = *(const uint4*)((const char*)hrep + hbyte + q*16);

    float pa = 0.f, pb = 0.f;   // owned rows: j=ks and j=ks+8

    // register rows 0..13
    #pragma unroll
    for (int j = 0; j < RROWS; ++j) {
      float rs = 0.f;
      #pragma unroll
      for (int q = 0; q < 4; ++q) rs = dot8(rs, wr[j*4 + q], hv[q]);
      rs = reduce8(rs);
      if (j < 8) { pa = (ks == j) ? rs : pa; }
      else       { pb = (ks == j - 8) ? rs : pb; }
    }
    // LDS rows 14,15 (per-lane-distinct b128 reads; compiler pipelines lgkmcnt)
    #pragma unroll
    for (int j = 0; j < LROWS; ++j) {
      float rs = 0.f;
      #pragma unroll
      for (int q = 0; q < 4; ++q) rs = dot8(rs, wl[(j*4 + q)*512 + t], hv[q]);
      rs = reduce8(rs);
      pb = (ks == 6 + j) ? rs : pb;
    }

    // distributed activation (wave-uniform gate -> scalar branch)
    float va = pa + xva, vb = pb + xvb;
    float aa, ab;
    if (isG) { aa = tanh_f(va);    ab = tanh_f(vb);    }
    else     { aa = sigmoid_f(va); ab = sigmoid_f(vb); }
    pre[preS + ks]     = aa;
    pre[preS + 8 + ks] = ab;
    __syncthreads();

    if (t < 256) {                 // tail: unit t (short: no exp chains left)
      float ig = pre[t], fg = pre[256 + t], gg = pre[512 + t], og = pre[768 + t];
      cst = fg*cst + ig*gg;
      float hval = og*tanh_f(cst);
      f16 hf = (f16)hval;
      #pragma unroll
      for (int cpy = 0; cpy < 4; ++cpy) hrep[cpy*264 + t] = hf;
      outp[(size_t)s*512 + t] = hf;
    }
    __syncthreads();
  }
}

// ---------------- mean pool + k,v projection ----------------
__global__ __launch_bounds__(256) void pool_kv_kernel(
    const f16* __restrict__ out_sum, const int* __restrict__ len_sum,
    const float* __restrict__ Wk, const float* __restrict__ Wv,
    float* __restrict__ kb, float* __restrict__ vb)
{
  const int b = blockIdx.x, t = threadIdx.x;
  __shared__ float sv[512];
  int len = len_sum[b]; if (len < 1) len = 1;
  float a0 = 0.f, a1 = 0.f;
  for (int s = 0; s < len; ++s) {
    const f16* row = out_sum + ((size_t)b*SSUM + s)*512;
    a0 += (float)row[t];
    a1 += (float)row[t+256];
  }
  float inv = 1.f/(float)len;
  sv[t] = a0*inv; sv[t+256] = a1*inv;
  __syncthreads();
  #pragma unroll
  for (int half = 0; half < 2; ++half) {
    int o = t + half*256;
    int h = o >> 7, dh = o & 127;
    const float* wkp = Wk + (size_t)h*512*128 + dh;
    const float* wvp = Wv + (size_t)h*512*128 + dh;
    float ak = 0.f, av = 0.f;
    for (int e2 = 0; e2 < 512; ++e2) {
      float sve = sv[e2];
      ak += sve*wkp[(size_t)e2*128];
      av += sve*wvp[(size_t)e2*128];
    }
    kb[((size_t)h*32 + b)*128 + dh] = ak;
    vb[((size_t)h*32 + b)*128 + dh] = av;
  }
}

// ---------------- scores + softmax ----------------
__global__ __launch_bounds__(256) void attn_kernel(
    const float* __restrict__ q, const float* __restrict__ kb, float* __restrict__ attn)
{
  const int hb = blockIdx.x;          // h*32 + b
  const int h = hb >> 5, b = hb & 31;
  const int t = threadIdx.x;
  __shared__ __align__(16) float kk[128];
  __shared__ float red[4];
  if (t < 128) kk[t] = kb[(size_t)hb*128 + t];
  __syncthreads();
  float vals[4];
  #pragma unroll
  for (int i = 0; i < 4; ++i) {
    int s = t + i*256;
    const float4* qp = (const float4*)(q + ((size_t)b*1024 + s)*512 + h*128);
    const float4* kp = (const float4*)kk;
    float a = 0.f;
    #pragma unroll
    for (int e2 = 0; e2 < 32; ++e2) {
      float4 qq = qp[e2], kx = kp[e2];
      a += qq.x*kx.x + qq.y*kx.y + qq.z*kx.z + qq.w*kx.w;
    }
    vals[i] = a;
  }
  float m = fmaxf(fmaxf(vals[0], vals[1]), fmaxf(vals[2], vals[3]));
  for (int o = 1; o < 64; o <<= 1) m = fmaxf(m, __shfl_xor(m, o));
  if ((t & 63) == 0) red[t >> 6] = m;
  __syncthreads();
  m = fmaxf(fmaxf(red[0], red[1]), fmaxf(red[2], red[3]));
  __syncthreads();
  float ex[4], lsum = 0.f;
  #pragma unroll
  for (int i = 0; i < 4; ++i) { ex[i] = __expf(vals[i] - m); lsum += ex[i]; }
  for (int o = 1; o < 64; o <<= 1) lsum += __shfl_xor(lsum, o);
  if ((t & 63) == 0) red[t >> 6] = lsum;
  __syncthreads();
  float inv = 1.f/(red[0] + red[1] + red[2] + red[3]);
  #pragma unroll
  for (int i = 0; i < 4; ++i) attn[(size_t)hb*1024 + t + i*256] = ex[i]*inv;
}

// ---------------- final: out = q + attn * v ----------------
__global__ __launch_bounds__(256) void final_kernel(
    float* __restrict__ out, const float* __restrict__ attn, const float* __restrict__ vb)
{
  const size_t TOT4 = (size_t)32*1024*512/4;
  const size_t stride = (size_t)gridDim.x*blockDim.x;
  for (size_t i = (size_t)blockIdx.x*blockDim.x + threadIdx.x; i < TOT4; i += stride) {
    int c4 = (int)(i & 127);
    int h = c4 >> 5;
    size_t srow = i >> 7;
    int b = (int)(srow >> 10), s = (int)(srow & 1023);
    float a = attn[((size_t)h*32 + b)*1024 + s];
    float4 vv = ((const float4*)vb)[((size_t)h*32 + b)*32 + (c4 & 31)];
    float4 qq = ((float4*)out)[i];
    qq.x += a*vv.x; qq.y += a*vv.y; qq.z += a*vv.z; qq.w += a*vv.w;
    ((float4*)out)[i] = qq;
  }
}

// ---------------- launch ----------------
extern "C" void kernel_launch(void* const* d_in, const int* in_sizes, int n_in,
                              void* d_out, int out_size, void* d_ws, size_t ws_size,
                              hipStream_t stream)
{
  const float* in_raw = (const float*)d_in[0];
  const float* in_sum = (const float*)d_in[1];
  const int*  len_sum = (const int*)d_in[3];
  const float* rf_wih = (const float*)d_in[4];
  const float* rf_whh = (const float*)d_in[5];
  const float* rf_b   = (const float*)d_in[6];
  const float* rb_wih = (const float*)d_in[7];
  const float* rb_whh = (const float*)d_in[8];
  const float* rb_b   = (const float*)d_in[9];
  const float* sf_wih = (const float*)d_in[10];
  const float* sf_whh = (const float*)d_in[11];
  const float* sf_b   = (const float*)d_in[12];
  const float* sb_wih = (const float*)d_in[13];
  const float* sb_whh = (const float*)d_in[14];
  const float* sb_b   = (const float*)d_in[15];
  const float* wq     = (const float*)d_in[16];
  const float* wk     = (const float*)d_in[17];
  const float* wv     = (const float*)d_in[18];

  if (ws_size < WS_NEED) return;

  char* ws = (char*)d_ws;
  f16* xg_raw_p  = (f16*)(ws + OFF_XG_RAW);
  f16* xg_sum_p  = (f16*)(ws + OFF_XG_SUM);
  f16* out_raw_p = (f16*)(ws + OFF_OUT_RAW);
  f16* out_sum_p = (f16*)(ws + OFF_OUT_SUM);
  f16* a_raw_p   = (f16*)(ws + OFF_A_RAW);
  f16* a_sum_p   = (f16*)(ws + OFF_A_SUM);
  f16* bih_raw_p = (f16*)(ws + OFF_BIH_RAW);
  f16* bih_sum_p = (f16*)(ws + OFF_BIH_SUM);
  f16* whh16_p   = (f16*)(ws + OFF_WHH);
  f16* wq16_p    = (f16*)(ws + OFF_WQ);
  float* kb_p    = (float*)(ws + OFF_KB);
  float* vb_p    = (float*)(ws + OFF_VB);
  float* attn_p  = (float*)(ws + OFF_ATTN);
  float* qout    = (float*)d_out;

  pack_kernel<<<4096, 256, 0, stream>>>(
      in_raw, in_sum, rf_wih, rb_wih, sf_wih, sb_wih,
      rf_whh, rb_whh, sf_whh, sb_whh, wq,
      a_raw_p, a_sum_p, bih_raw_p, bih_sum_p, whh16_p, wq16_p);

  gemm_kernel<1><<<dim3(256, 16), 256, 0, stream>>>(
      a_raw_p, bih_raw_p, nullptr, xg_raw_p, rf_b, rb_b, KP, 0, (size_t)32*1024*1024);
  gemm_kernel<1><<<dim3(32, 16), 256, 0, stream>>>(
      a_sum_p, bih_sum_p, nullptr, xg_sum_p, sf_b, sb_b, KP, 0, (size_t)32*128*1024);

  lstm_kernel<<<128, 512, 0, stream>>>(whh16_p, xg_raw_p, xg_sum_p, out_raw_p, out_sum_p);

  gemm_kernel<0><<<dim3(256, 4), 256, 0, stream>>>(
      out_raw_p, wq16_p, qout, nullptr, nullptr, nullptr, 512, 512, 0);

  pool_kv_kernel<<<32, 256, 0, stream>>>(out_sum_p, len_sum, wk, wv, kb_p, vb_p);
  attn_kernel<<<128, 256, 0, stream>>>(qout, kb_p, attn_p);
  final_kernel<<<4096, 256, 0, stream>>>(qout, attn_p, vb_p);
}

// Round 12
// 2143.071 us; speedup vs baseline: 3.4039x; 1.0286x over previous
//
#include <hip/hip_runtime.h>

typedef _Float16 f16;
typedef _Float16 half2t __attribute__((ext_vector_type(2)));
typedef _Float16 half8 __attribute__((ext_vector_type(8)));
typedef float f32x4 __attribute__((ext_vector_type(4)));

#define KP 320
#define DIN 300
#define SRAW 1024
#define SSUM 128

// ---------------- workspace layout (bytes) ----------------
static constexpr size_t OFF_XG_RAW  = 0;                                        // f16 [2][32][1024][1024] natural gate-major
static constexpr size_t OFF_XG_SUM  = OFF_XG_RAW + (size_t)2*32*1024*1024*2;    // f16 [2][32][128][1024]
static constexpr size_t OFF_OUT_RAW = OFF_XG_SUM + (size_t)2*32*128*1024*2;     // f16 [32][1024][512]
static constexpr size_t OFF_OUT_SUM = OFF_OUT_RAW + (size_t)32*1024*512*2;      // f16 [32][128][512]
static constexpr size_t OFF_A_RAW   = OFF_OUT_SUM + (size_t)32*128*512*2;       // f16 [32768][320]
static constexpr size_t OFF_A_SUM   = OFF_A_RAW + (size_t)32768*KP*2;           // f16 [4096][320]
static constexpr size_t OFF_BIH_RAW = OFF_A_SUM + (size_t)4096*KP*2;            // f16 [2048][320]
static constexpr size_t OFF_BIH_SUM = OFF_BIH_RAW + (size_t)2048*KP*2;          // f16 [2048][320]
static constexpr size_t OFF_WHH     = OFF_BIH_SUM + (size_t)2048*KP*2;          // f16 [4][64][512][8] chunk layout
static constexpr size_t OFF_WQ      = OFF_WHH + (size_t)4*64*512*8*2;           // f16 [512][512]
static constexpr size_t OFF_KB      = OFF_WQ + (size_t)512*512*2;               // f32 [4][32][128]
static constexpr size_t OFF_VB      = OFF_KB + (size_t)4*32*128*4;              // f32 [4][32][128]
static constexpr size_t OFF_ATTN    = OFF_VB + (size_t)4*32*128*4;              // f32 [4][32][1024]
static constexpr size_t WS_NEED     = OFF_ATTN + (size_t)4*32*1024*4;           // ~208 MB

// ---------------- pack / convert ----------------
// Whh chunk layout: [ed][c(64)][t(512)][8 f16]; thread t (rg=t>>3, ks=t&7),
// chunk c = j*4+q holds W[row(rg,j)][ks*32+q*8 .. +8), j in [0,16), q in [0,4),
// row(rg,j) = (j&3)*256 + rg*4 + (j>>2)  -- gate (j&3) of unit rg*4+(j>>2).
__global__ void pack_kernel(
    const float* __restrict__ in_raw, const float* __restrict__ in_sum,
    const float* __restrict__ wih_rf, const float* __restrict__ wih_rb,
    const float* __restrict__ wih_sf, const float* __restrict__ wih_sb,
    const float* __restrict__ whh_rf, const float* __restrict__ whh_rb,
    const float* __restrict__ whh_sf, const float* __restrict__ whh_sb,
    const float* __restrict__ wq,
    f16* __restrict__ a_raw, f16* __restrict__ a_sum,
    f16* __restrict__ bih_raw, f16* __restrict__ bih_sum,
    f16* __restrict__ whh16, f16* __restrict__ wq16)
{
  constexpr size_t N1 = (size_t)32768*KP;
  constexpr size_t N2 = (size_t)4096*KP;
  constexpr size_t N3 = (size_t)2048*KP;
  constexpr size_t N5 = (size_t)4*64*512*8;
  constexpr size_t N6 = (size_t)512*512;
  const size_t TOT = N1+N2+N3+N3+N5+N6;
  const size_t stride = (size_t)gridDim.x*blockDim.x;
  for (size_t i = (size_t)blockIdx.x*blockDim.x + threadIdx.x; i < TOT; i += stride) {
    size_t j = i;
    if (j < N1) {
      size_t m = j/KP, k = j - m*KP;
      a_raw[j] = (f16)(k < DIN ? in_raw[m*DIN + k] : 0.f);
      continue;
    }
    j -= N1;
    if (j < N2) {
      size_t m = j/KP, k = j - m*KP;
      a_sum[j] = (f16)(k < DIN ? in_sum[m*DIN + k] : 0.f);
      continue;
    }
    j -= N2;
    if (j < N3) {
      size_t n = j/KP, k = j - n*KP;
      float v = 0.f;
      if (k < DIN) v = (n < 1024) ? wih_rf[n*DIN + k] : wih_rb[(n-1024)*DIN + k];
      bih_raw[j] = (f16)v;
      continue;
    }
    j -= N3;
    if (j < N3) {
      size_t n = j/KP, k = j - n*KP;
      float v = 0.f;
      if (k < DIN) v = (n < 1024) ? wih_sf[n*DIN + k] : wih_sb[(n-1024)*DIN + k];
      bih_sum[j] = (f16)v;
      continue;
    }
    j -= N3;
    if (j < N5) {
      int ed = (int)(j >> 18);
      int c  = (int)((j >> 12) & 63);
      int t  = (int)((j >> 3) & 511);
      int ii = (int)(j & 7);
      int jrow = c >> 2, q = c & 3;
      int rg = t >> 3, ks = t & 7;
      int row = (jrow & 3)*256 + rg*4 + (jrow >> 2);
      int col = ks*32 + q*8 + ii;
      const float* src = (ed==0)?whh_rf:(ed==1)?whh_rb:(ed==2)?whh_sf:whh_sb;
      whh16[j] = (f16)src[(size_t)row*256 + col];
      continue;
    }
    j -= N5;
    {
      int n = (int)(j >> 9), k = (int)(j & 511);
      int h = n >> 7, dh = n & 127;
      wq16[j] = (f16)wq[((size_t)h*512 + k)*128 + dh];
    }
  }
}

// ---------------- f16 MFMA GEMM: C[M,N] = A[M,K] * B[N,K]^T ----------------
// EPI 0: plain f32 store.  EPI 1: +bias, f16 store split by dir, natural layout.
template<int EPI>
__global__ __launch_bounds__(256) void gemm_kernel(
    const f16* __restrict__ A, const f16* __restrict__ Bm,
    float* __restrict__ Cf, f16* __restrict__ Cx,
    const float* __restrict__ bias0, const float* __restrict__ bias1,
    int K, int ldcN, size_t dirStride)
{
  __shared__ __align__(16) f16 As[128*40];
  __shared__ __align__(16) f16 Bs[128*40];
  const int tid = threadIdx.x;
  const int m0 = blockIdx.x*128, n0 = blockIdx.y*128;
  const int w = tid >> 6, lane = tid & 63;
  const int wm = w >> 1, wn = w & 1;
  const int lr = lane & 15, lk = lane >> 4;
  f32x4 acc[4][4] = {};
  const int nsteps = K >> 5;
  for (int kt = 0; kt < nsteps; ++kt) {
    __syncthreads();
    #pragma unroll
    for (int it = 0; it < 2; ++it) {
      int c = tid + it*256;
      int r = c >> 2, kc = c & 3;
      *(uint4*)&As[r*40 + kc*8] = *(const uint4*)&A[(size_t)(m0+r)*K + kt*32 + kc*8];
      *(uint4*)&Bs[r*40 + kc*8] = *(const uint4*)&Bm[(size_t)(n0+r)*K + kt*32 + kc*8];
    }
    __syncthreads();
    half8 af[4], bf[4];
    #pragma unroll
    for (int mt = 0; mt < 4; ++mt) af[mt] = *(const half8*)&As[(wm*64 + mt*16 + lr)*40 + lk*8];
    #pragma unroll
    for (int nt = 0; nt < 4; ++nt) bf[nt] = *(const half8*)&Bs[(wn*64 + nt*16 + lr)*40 + lk*8];
    #pragma unroll
    for (int mt = 0; mt < 4; ++mt)
      #pragma unroll
      for (int nt = 0; nt < 4; ++nt)
        acc[mt][nt] = __builtin_amdgcn_mfma_f32_16x16x32_f16(af[mt], bf[nt], acc[mt][nt], 0, 0, 0);
  }
  const int rb = lk*4;
  #pragma unroll
  for (int mt = 0; mt < 4; ++mt) {
    #pragma unroll
    for (int nt = 0; nt < 4; ++nt) {
      int n = n0 + wn*64 + nt*16 + lr;
      int mloc = m0 + wm*64 + mt*16 + rb;
      if (EPI == 0) {
        #pragma unroll
        for (int r = 0; r < 4; ++r)
          Cf[(size_t)(mloc+r)*ldcN + n] = acc[mt][nt][r];
      } else {
        int dir = n >> 10, cc = n & 1023;
        float bs = (dir ? bias1 : bias0)[cc];
        f16* dst = Cx + (size_t)dir*dirStride;
        #pragma unroll
        for (int r = 0; r < 4; ++r)
          dst[(size_t)(mloc+r)*1024 + cc] = (f16)(acc[mt][nt][r] + bs);
      }
    }
  }
}

// ---------------- LSTM recurrence (lane k-sliced, unit-pair ownership) ----------------
// 1 WG (512 threads) per (e,d,b). Thread t: rg=t>>3, ks=t&7. Group rg handles
// units rg*4..rg*4+3 (16 rows = 4 units x 4 gates). After reduce8, lane ks keeps
// rows j=2ks (pa) and j=2ks+1 (pb): gates (ks&1)*2, (ks&1)*2+1 of unit
// rg*4+(ks>>1). Lane pair (even,odd) = gates (i,f)/(g,o) of ONE unit:
// activations distributed+branchless, gates exchanged via DPP lane^1, c/h
// replicated per pair, h double-buffered by parity -> ONE barrier per step.
#define RROWS 13
#define LROWS 3

__device__ __forceinline__ float dot8(float acc, uint4 wv, uint4 hv) {
#if __has_builtin(__builtin_amdgcn_fdot2)
  union { uint4 u; half2t h[4]; } W, Hh;
  W.u = wv; Hh.u = hv;
  #pragma unroll
  for (int i = 0; i < 4; ++i) acc = __builtin_amdgcn_fdot2(W.h[i], Hh.h[i], acc, false);
#else
  union { uint4 u; f16 h[8]; } W, Hh;
  W.u = wv; Hh.u = hv;
  #pragma unroll
  for (int i = 0; i < 8; ++i) acc += (float)W.h[i]*(float)Hh.h[i];
#endif
  return acc;
}

__device__ __forceinline__ float tanh_f(float x) {
  float e = __expf(2.f * x);
  return 1.f - 2.f * __builtin_amdgcn_rcpf(e + 1.f);
}

__device__ __forceinline__ void pin4(uint4& v) {
  asm volatile("" : "+v"(v.x), "+v"(v.y), "+v"(v.z), "+v"(v.w));
}

// DPP helpers over the 8-lane k-slice group (VALU pipe, no LDS).
template<int CTRL>
__device__ __forceinline__ float dpp_add(float v) {
  int m = __builtin_amdgcn_update_dpp(0, __builtin_bit_cast(int, v), CTRL, 0xf, 0xf, true);
  return v + __builtin_bit_cast(float, m);
}
template<int CTRL>
__device__ __forceinline__ float dpp_mov(float v) {
  int m = __builtin_amdgcn_update_dpp(0, __builtin_bit_cast(int, v), CTRL, 0xf, 0xf, true);
  return __builtin_bit_cast(float, m);
}
__device__ __forceinline__ float reduce8(float v) {
  v = dpp_add<0xB1>(v);   // quad_perm [1,0,3,2]  : lane ^ 1
  v = dpp_add<0x4E>(v);   // quad_perm [2,3,0,1]  : lane ^ 2
  v = dpp_add<0x141>(v);  // row_half_mirror      : cross 4-group within 8
  return v;
}

__global__ void __launch_bounds__(512, 2) __attribute__((amdgpu_waves_per_eu(2, 2)))
lstm_kernel(
    const f16* __restrict__ whh16,
    const f16* __restrict__ xg_raw, const f16* __restrict__ xg_sum,
    f16* __restrict__ out_raw, f16* __restrict__ out_sum)
{
  const int wg = blockIdx.x;               // [e(1)][d(1)][b(5)]
  const int e = wg >> 6, r2 = wg & 63, d = r2 >> 5, b = r2 & 31;
  const int S = e ? SSUM : SRAW;
  const int t = threadIdx.x;
  const int rg = t >> 3, ks = t & 7;
  const uint4* wb = (const uint4*)(whh16 + (size_t)(e*2+d)*(64*512*8));
  const f16* xg = (e ? xg_sum : xg_raw) + ((size_t)(d*32 + b))*(size_t)S*1024;
  f16* outp = (e ? out_sum : out_raw) + (size_t)b*S*512 + d*256;

  __shared__ __align__(16) uint4 wl[LROWS*4*512];   // 96 KB: rows 13..15
  __shared__ __align__(16) f16 hrep[2][4*264];       // parity-dbuf, 4 padded copies

  // stage LDS weight rows (chunks 52..63)
  #pragma unroll
  for (int c = 0; c < LROWS*4; ++c) wl[c*512 + t] = wb[(RROWS*4 + c)*512 + t];
  // register weight rows 0..12 (chunks 0..51), pinned against rematerialization
  uint4 wr[RROWS*4];
  #pragma unroll
  for (int c = 0; c < RROWS*4; ++c) wr[c] = wb[c*512 + t];
  #pragma unroll
  for (int c = 0; c < RROWS*4; ++c) pin4(wr[c]);

  if (t < 256) {
    #pragma unroll
    for (int cpy = 0; cpy < 4; ++cpy) hrep[0][cpy*264 + t] = (f16)0.f;
  }
  float cst = 0.f;
  const int hbyte = (ks >> 1)*528 + ks*64;    // conflict-free slice base
  const int isOdd = ks & 1;
  const int unit = rg*4 + (ks >> 1);          // own unit (shared with lane^1)
  const int ua = isOdd*512 + unit;            // xg row of gate (isOdd?g:i)
  // branchless activation constants: aa = Ac*sigmoid(Bc*va)+Cc
  // even lane: gate i (sigmoid: A=1,B=1,C=0); odd lane: gate g (tanh: A=2,B=2,C=-1)
  const float Ac = isOdd ? 2.f : 1.f;
  const float Bc = isOdd ? 2.f : 1.f;
  const float Cc = isOdd ? -1.f : 0.f;
  __syncthreads();

  for (int st = 0; st < S; ++st) {
    const int s = d ? (S - 1 - st) : st;
    const int par = st & 1;

    // xg terms for this thread's two gates (issued early, consumed post-dots)
    float xva = (float)xg[(size_t)s*1024 + ua];
    float xvb = (float)xg[(size_t)s*1024 + ua + 256];

    // h slice (32 elems) from replicated parity buffer — conflict-free
    uint4 hv[4];
    #pragma unroll
    for (int q = 0; q < 4; ++q)
      hv[q] = *(const uint4*)((const char*)hrep[par] + hbyte + q*16);

    float pa = 0.f, pb = 0.f;   // owned rows: j=2ks, j=2ks+1

    // register rows 0..12
    #pragma unroll
    for (int j = 0; j < RROWS; ++j) {
      float rs = 0.f;
      #pragma unroll
      for (int q = 0; q < 4; ++q) rs = dot8(rs, wr[j*4 + q], hv[q]);
      rs = reduce8(rs);
      if (j & 1) pb = (ks == (j >> 1)) ? rs : pb;
      else       pa = (ks == (j >> 1)) ? rs : pa;
    }
    // LDS rows 13..15
    #pragma unroll
    for (int jj = 0; jj < LROWS; ++jj) {
      float rs = 0.f;
      #pragma unroll
      for (int q = 0; q < 4; ++q) rs = dot8(rs, wl[(jj*4 + q)*512 + t], hv[q]);
      rs = reduce8(rs);
      const int j = RROWS + jj;
      if (j & 1) pb = (ks == (j >> 1)) ? rs : pb;
      else       pa = (ks == (j >> 1)) ? rs : pa;
    }

    // distributed branchless activations (one exp chain each)
    float va = pa + xva, vb = pb + xvb;
    float aa = Ac*__builtin_amdgcn_rcpf(1.f + __expf(-Bc*va)) + Cc;  // i or g(tanh)
    float ab = __builtin_amdgcn_rcpf(1.f + __expf(-vb));             // f or o

    // pair exchange: lane^1 holds the other two gates of the same unit
    float paa = dpp_mov<0xB1>(aa);
    float pab = dpp_mov<0xB1>(ab);
    float ig = isOdd ? paa : aa;
    float fg = isOdd ? pab : ab;
    float gg = isOdd ? aa : paa;
    float og = isOdd ? ab : pab;
    cst = fg*cst + ig*gg;                       // replicated per pair (bit-identical)
    float hval = og*tanh_f(cst);
    f16 hf = (f16)hval;
    if (!isOdd) {
      #pragma unroll
      for (int cpy = 0; cpy < 4; ++cpy) hrep[par ^ 1][cpy*264 + unit] = hf;
      outp[(size_t)s*512 + unit] = hf;
    }
    __syncthreads();   // single barrier: write-buf[par^1] visible before next reads
  }
}

// ---------------- mean pool + k,v projection ----------------
__global__ __launch_bounds__(256) void pool_kv_kernel(
    const f16* __restrict__ out_sum, const int* __restrict__ len_sum,
    const float* __restrict__ Wk, const float* __restrict__ Wv,
    float* __restrict__ kb, float* __restrict__ vb)
{
  const int b = blockIdx.x, t = threadIdx.x;
  __shared__ float sv[512];
  int len = len_sum[b]; if (len < 1) len = 1;
  float a0 = 0.f, a1 = 0.f;
  for (int s = 0; s < len; ++s) {
    const f16* row = out_sum + ((size_t)b*SSUM + s)*512;
    a0 += (float)row[t];
    a1 += (float)row[t+256];
  }
  float inv = 1.f/(float)len;
  sv[t] = a0*inv; sv[t+256] = a1*inv;
  __syncthreads();
  #pragma unroll
  for (int half = 0; half < 2; ++half) {
    int o = t + half*256;
    int h = o >> 7, dh = o & 127;
    const float* wkp = Wk + (size_t)h*512*128 + dh;
    const float* wvp = Wv + (size_t)h*512*128 + dh;
    float ak = 0.f, av = 0.f;
    for (int e2 = 0; e2 < 512; ++e2) {
      float sve = sv[e2];
      ak += sve*wkp[(size_t)e2*128];
      av += sve*wvp[(size_t)e2*128];
    }
    kb[((size_t)h*32 + b)*128 + dh] = ak;
    vb[((size_t)h*32 + b)*128 + dh] = av;
  }
}

// ---------------- scores + softmax ----------------
__global__ __launch_bounds__(256) void attn_kernel(
    const float* __restrict__ q, const float* __restrict__ kb, float* __restrict__ attn)
{
  const int hb = blockIdx.x;          // h*32 + b
  const int h = hb >> 5, b = hb & 31;
  const int t = threadIdx.x;
  __shared__ __align__(16) float kk[128];
  __shared__ float red[4];
  if (t < 128) kk[t] = kb[(size_t)hb*128 + t];
  __syncthreads();
  float vals[4];
  #pragma unroll
  for (int i = 0; i < 4; ++i) {
    int s = t + i*256;
    const float4* qp = (const float4*)(q + ((size_t)b*1024 + s)*512 + h*128);
    const float4* kp = (const float4*)kk;
    float a = 0.f;
    #pragma unroll
    for (int e2 = 0; e2 < 32; ++e2) {
      float4 qq = qp[e2], kx = kp[e2];
      a += qq.x*kx.x + qq.y*kx.y + qq.z*kx.z + qq.w*kx.w;
    }
    vals[i] = a;
  }
  float m = fmaxf(fmaxf(vals[0], vals[1]), fmaxf(vals[2], vals[3]));
  for (int o = 1; o < 64; o <<= 1) m = fmaxf(m, __shfl_xor(m, o));
  if ((t & 63) == 0) red[t >> 6] = m;
  __syncthreads();
  m = fmaxf(fmaxf(red[0], red[1]), fmaxf(red[2], red[3]));
  __syncthreads();
  float ex[4], lsum = 0.f;
  #pragma unroll
  for (int i = 0; i < 4; ++i) { ex[i] = __expf(vals[i] - m); lsum += ex[i]; }
  for (int o = 1; o < 64; o <<= 1) lsum += __shfl_xor(lsum, o);
  if ((t & 63) == 0) red[t >> 6] = lsum;
  __syncthreads();
  float inv = 1.f/(red[0] + red[1] + red[2] + red[3]);
  #pragma unroll
  for (int i = 0; i < 4; ++i) attn[(size_t)hb*1024 + t + i*256] = ex[i]*inv;
}

// ---------------- final: out = q + attn * v ----------------
__global__ __launch_bounds__(256) void final_kernel(
    float* __restrict__ out, const float* __restrict__ attn, const float* __restrict__ vb)
{
  const size_t TOT4 = (size_t)32*1024*512/4;
  const size_t stride = (size_t)gridDim.x*blockDim.x;
  for (size_t i = (size_t)blockIdx.x*blockDim.x + threadIdx.x; i < TOT4; i += stride) {
    int c4 = (int)(i & 127);
    int h = c4 >> 5;
    size_t srow = i >> 7;
    int b = (int)(srow >> 10), s = (int)(srow & 1023);
    float a = attn[((size_t)h*32 + b)*1024 + s];
    float4 vv = ((const float4*)vb)[((size_t)h*32 + b)*32 + (c4 & 31)];
    float4 qq = ((float4*)out)[i];
    qq.x += a*vv.x; qq.y += a*vv.y; qq.z += a*vv.z; qq.w += a*vv.w;
    ((float4*)out)[i] = qq;
  }
}

// ---------------- launch ----------------
extern "C" void kernel_launch(void* const* d_in, const int* in_sizes, int n_in,
                              void* d_out, int out_size, void* d_ws, size_t ws_size,
                              hipStream_t stream)
{
  const float* in_raw = (const float*)d_in[0];
  const float* in_sum = (const float*)d_in[1];
  const int*  len_sum = (const int*)d_in[3];
  const float* rf_wih = (const float*)d_in[4];
  const float* rf_whh = (const float*)d_in[5];
  const float* rf_b   = (const float*)d_in[6];
  const float* rb_wih = (const float*)d_in[7];
  const float* rb_whh = (const float*)d_in[8];
  const float* rb_b   = (const float*)d_in[9];
  const float* sf_wih = (const float*)d_in[10];
  const float* sf_whh = (const float*)d_in[11];
  const float* sf_b   = (const float*)d_in[12];
  const float* sb_wih = (const float*)d_in[13];
  const float* sb_whh = (const float*)d_in[14];
  const float* sb_b   = (const float*)d_in[15];
  const float* wq     = (const float*)d_in[16];
  const float* wk     = (const float*)d_in[17];
  const float* wv     = (const float*)d_in[18];

  if (ws_size < WS_NEED) return;

  char* ws = (char*)d_ws;
  f16* xg_raw_p  = (f16*)(ws + OFF_XG_RAW);
  f16* xg_sum_p  = (f16*)(ws + OFF_XG_SUM);
  f16* out_raw_p = (f16*)(ws + OFF_OUT_RAW);
  f16* out_sum_p = (f16*)(ws + OFF_OUT_SUM);
  f16* a_raw_p   = (f16*)(ws + OFF_A_RAW);
  f16* a_sum_p   = (f16*)(ws + OFF_A_SUM);
  f16* bih_raw_p = (f16*)(ws + OFF_BIH_RAW);
  f16* bih_sum_p = (f16*)(ws + OFF_BIH_SUM);
  f16* whh16_p   = (f16*)(ws + OFF_WHH);
  f16* wq16_p    = (f16*)(ws + OFF_WQ);
  float* kb_p    = (float*)(ws + OFF_KB);
  float* vb_p    = (float*)(ws + OFF_VB);
  float* attn_p  = (float*)(ws + OFF_ATTN);
  float* qout    = (float*)d_out;

  pack_kernel<<<4096, 256, 0, stream>>>(
      in_raw, in_sum, rf_wih, rb_wih, sf_wih, sb_wih,
      rf_whh, rb_whh, sf_whh, sb_whh, wq,
      a_raw_p, a_sum_p, bih_raw_p, bih_sum_p, whh16_p, wq16_p);

  gemm_kernel<1><<<dim3(256, 16), 256, 0, stream>>>(
      a_raw_p, bih_raw_p, nullptr, xg_raw_p, rf_b, rb_b, KP, 0, (size_t)32*1024*1024);
  gemm_kernel<1><<<dim3(32, 16), 256, 0, stream>>>(
      a_sum_p, bih_sum_p, nullptr, xg_sum_p, sf_b, sb_b, KP, 0, (size_t)32*128*1024);

  lstm_kernel<<<128, 512, 0, stream>>>(whh16_p, xg_raw_p, xg_sum_p, out_raw_p, out_sum_p);

  gemm_kernel<0><<<dim3(256, 4), 256, 0, stream>>>(
      out_raw_p, wq16_p, qout, nullptr, nullptr, nullptr, 512, 512, 0);

  pool_kv_kernel<<<32, 256, 0, stream>>>(out_sum_p, len_sum, wk, wv, kb_p, vb_p);
  attn_kernel<<<128, 256, 0, stream>>>(qout, kb_p, attn_p);
  final_kernel<<<4096, 256, 0, stream>>>(qout, attn_p, vb_p);
}

// Round 13
// 2071.695 us; speedup vs baseline: 3.5211x; 1.0345x over previous
//
#include <hip/hip_runtime.h>

typedef _Float16 f16;
typedef _Float16 half2t __attribute__((ext_vector_type(2)));
typedef _Float16 half8 __attribute__((ext_vector_type(8)));
typedef float f32x4 __attribute__((ext_vector_type(4)));

#define KP 320
#define DIN 300
#define SRAW 1024
#define SSUM 128

// ---------------- workspace layout (bytes) ----------------
static constexpr size_t OFF_XG_RAW  = 0;                                        // f16 [2][32][1024][1024] (u*4+gate interleave)
static constexpr size_t OFF_XG_SUM  = OFF_XG_RAW + (size_t)2*32*1024*1024*2;    // f16 [2][32][128][1024]
static constexpr size_t OFF_OUT_RAW = OFF_XG_SUM + (size_t)2*32*128*1024*2;     // f16 [32][1024][512]
static constexpr size_t OFF_OUT_SUM = OFF_OUT_RAW + (size_t)32*1024*512*2;      // f16 [32][128][512]
static constexpr size_t OFF_A_RAW   = OFF_OUT_SUM + (size_t)32*128*512*2;       // f16 [32768][320]
static constexpr size_t OFF_A_SUM   = OFF_A_RAW + (size_t)32768*KP*2;           // f16 [4096][320]
static constexpr size_t OFF_BIH_RAW = OFF_A_SUM + (size_t)4096*KP*2;            // f16 [2048][320]
static constexpr size_t OFF_BIH_SUM = OFF_BIH_RAW + (size_t)2048*KP*2;          // f16 [2048][320]
static constexpr size_t OFF_WHH     = OFF_BIH_SUM + (size_t)2048*KP*2;          // f16 [4][64][512][8] chunk layout
static constexpr size_t OFF_WQ      = OFF_WHH + (size_t)4*64*512*8*2;           // f16 [512][512]
static constexpr size_t OFF_KB      = OFF_WQ + (size_t)512*512*2;               // f32 [4][32][128]
static constexpr size_t OFF_VB      = OFF_KB + (size_t)4*32*128*4;              // f32 [4][32][128]
static constexpr size_t OFF_ATTN    = OFF_VB + (size_t)4*32*128*4;              // f32 [4][32][1024] (unused; kept for layout stability)
static constexpr size_t WS_NEED     = OFF_ATTN + (size_t)4*32*1024*4;           // ~208 MB

// ---------------- pack / convert ----------------
// Whh chunk layout: [ed][c(64)][t(512)][8 f16], where for thread t (rg=t>>3, ks=t&7)
// chunk c = j*4+q holds W[rg*16+j][ks*32+q*8 .. +8)  -- j in [0,16), q in [0,4)
__global__ void pack_kernel(
    const float* __restrict__ in_raw, const float* __restrict__ in_sum,
    const float* __restrict__ wih_rf, const float* __restrict__ wih_rb,
    const float* __restrict__ wih_sf, const float* __restrict__ wih_sb,
    const float* __restrict__ whh_rf, const float* __restrict__ whh_rb,
    const float* __restrict__ whh_sf, const float* __restrict__ whh_sb,
    const float* __restrict__ wq,
    f16* __restrict__ a_raw, f16* __restrict__ a_sum,
    f16* __restrict__ bih_raw, f16* __restrict__ bih_sum,
    f16* __restrict__ whh16, f16* __restrict__ wq16)
{
  constexpr size_t N1 = (size_t)32768*KP;
  constexpr size_t N2 = (size_t)4096*KP;
  constexpr size_t N3 = (size_t)2048*KP;
  constexpr size_t N5 = (size_t)4*64*512*8;
  constexpr size_t N6 = (size_t)512*512;
  const size_t TOT = N1+N2+N3+N3+N5+N6;
  const size_t stride = (size_t)gridDim.x*blockDim.x;
  for (size_t i = (size_t)blockIdx.x*blockDim.x + threadIdx.x; i < TOT; i += stride) {
    size_t j = i;
    if (j < N1) {
      size_t m = j/KP, k = j - m*KP;
      a_raw[j] = (f16)(k < DIN ? in_raw[m*DIN + k] : 0.f);
      continue;
    }
    j -= N1;
    if (j < N2) {
      size_t m = j/KP, k = j - m*KP;
      a_sum[j] = (f16)(k < DIN ? in_sum[m*DIN + k] : 0.f);
      continue;
    }
    j -= N2;
    if (j < N3) {
      size_t n = j/KP, k = j - n*KP;
      float v = 0.f;
      if (k < DIN) v = (n < 1024) ? wih_rf[n*DIN + k] : wih_rb[(n-1024)*DIN + k];
      bih_raw[j] = (f16)v;
      continue;
    }
    j -= N3;
    if (j < N3) {
      size_t n = j/KP, k = j - n*KP;
      float v = 0.f;
      if (k < DIN) v = (n < 1024) ? wih_sf[n*DIN + k] : wih_sb[(n-1024)*DIN + k];
      bih_sum[j] = (f16)v;
      continue;
    }
    j -= N3;
    if (j < N5) {
      int ed = (int)(j >> 18);
      int c  = (int)((j >> 12) & 63);
      int t  = (int)((j >> 3) & 511);
      int ii = (int)(j & 7);
      int jrow = c >> 2, q = c & 3;
      int rg = t >> 3, ks = t & 7;
      int row = rg*16 + jrow;
      int col = ks*32 + q*8 + ii;
      const float* src = (ed==0)?whh_rf:(ed==1)?whh_rb:(ed==2)?whh_sf:whh_sb;
      whh16[j] = (f16)src[(size_t)row*256 + col];
      continue;
    }
    j -= N5;
    {
      int n = (int)(j >> 9), k = (int)(j & 511);
      int h = n >> 7, dh = n & 127;
      wq16[j] = (f16)wq[((size_t)h*512 + k)*128 + dh];
    }
  }
}

// ---------------- f16 MFMA GEMM (EPI 0): C[M,N] = A[M,K] * B[N,K]^T, f32 out ----------------
__global__ __launch_bounds__(256) void gemm_kernel(
    const f16* __restrict__ A, const f16* __restrict__ Bm,
    float* __restrict__ Cf, int K, int ldcN)
{
  __shared__ __align__(16) f16 As[128*40];
  __shared__ __align__(16) f16 Bs[128*40];
  const int tid = threadIdx.x;
  const int m0 = blockIdx.x*128, n0 = blockIdx.y*128;
  const int w = tid >> 6, lane = tid & 63;
  const int wm = w >> 1, wn = w & 1;
  const int lr = lane & 15, lk = lane >> 4;
  f32x4 acc[4][4] = {};
  const int nsteps = K >> 5;
  for (int kt = 0; kt < nsteps; ++kt) {
    __syncthreads();
    #pragma unroll
    for (int it = 0; it < 2; ++it) {
      int c = tid + it*256;
      int r = c >> 2, kc = c & 3;
      *(uint4*)&As[r*40 + kc*8] = *(const uint4*)&A[(size_t)(m0+r)*K + kt*32 + kc*8];
      *(uint4*)&Bs[r*40 + kc*8] = *(const uint4*)&Bm[(size_t)(n0+r)*K + kt*32 + kc*8];
    }
    __syncthreads();
    half8 af[4], bf[4];
    #pragma unroll
    for (int mt = 0; mt < 4; ++mt) af[mt] = *(const half8*)&As[(wm*64 + mt*16 + lr)*40 + lk*8];
    #pragma unroll
    for (int nt = 0; nt < 4; ++nt) bf[nt] = *(const half8*)&Bs[(wn*64 + nt*16 + lr)*40 + lk*8];
    #pragma unroll
    for (int mt = 0; mt < 4; ++mt)
      #pragma unroll
      for (int nt = 0; nt < 4; ++nt)
        acc[mt][nt] = __builtin_amdgcn_mfma_f32_16x16x32_f16(af[mt], bf[nt], acc[mt][nt], 0, 0, 0);
  }
  const int rb = lk*4;
  #pragma unroll
  for (int mt = 0; mt < 4; ++mt) {
    #pragma unroll
    for (int nt = 0; nt < 4; ++nt) {
      int n = n0 + wn*64 + nt*16 + lr;
      int mloc = m0 + wm*64 + mt*16 + rb;
      #pragma unroll
      for (int r = 0; r < 4; ++r)
        Cf[(size_t)(mloc+r)*ldcN + n] = acc[mt][nt][r];
    }
  }
}

// ---------------- merged bias-GEMMs (raw + sum) -> xg, [u*4+gate] interleave ----------------
// grid (288,16): x<256 -> raw problem (M=32768), x>=256 -> sum problem (M=4096).
__global__ __launch_bounds__(256) void gemm_dual_kernel(
    const f16* __restrict__ A1, const f16* __restrict__ B1,
    const f16* __restrict__ A2, const f16* __restrict__ B2,
    f16* __restrict__ C1, f16* __restrict__ C2,
    const float* __restrict__ b1f, const float* __restrict__ b1b,
    const float* __restrict__ b2f, const float* __restrict__ b2b)
{
  __shared__ __align__(16) f16 As[128*40];
  __shared__ __align__(16) f16 Bs[128*40];
  const bool second = (blockIdx.x >= 256);
  const f16* A  = second ? A2 : A1;
  const f16* Bm = second ? B2 : B1;
  f16* Cx       = second ? C2 : C1;
  const float* bias0 = second ? b2f : b1f;
  const float* bias1 = second ? b2b : b1b;
  const size_t dirStride = second ? (size_t)32*128*1024 : (size_t)32*1024*1024;
  const int m0 = (second ? ((int)blockIdx.x - 256) : (int)blockIdx.x)*128;
  const int n0 = blockIdx.y*128;
  const int tid = threadIdx.x;
  const int w = tid >> 6, lane = tid & 63;
  const int wm = w >> 1, wn = w & 1;
  const int lr = lane & 15, lk = lane >> 4;
  f32x4 acc[4][4] = {};
  const int nsteps = KP >> 5;
  for (int kt = 0; kt < nsteps; ++kt) {
    __syncthreads();
    #pragma unroll
    for (int it = 0; it < 2; ++it) {
      int c = tid + it*256;
      int r = c >> 2, kc = c & 3;
      *(uint4*)&As[r*40 + kc*8] = *(const uint4*)&A[(size_t)(m0+r)*KP + kt*32 + kc*8];
      *(uint4*)&Bs[r*40 + kc*8] = *(const uint4*)&Bm[(size_t)(n0+r)*KP + kt*32 + kc*8];
    }
    __syncthreads();
    half8 af[4], bf[4];
    #pragma unroll
    for (int mt = 0; mt < 4; ++mt) af[mt] = *(const half8*)&As[(wm*64 + mt*16 + lr)*40 + lk*8];
    #pragma unroll
    for (int nt = 0; nt < 4; ++nt) bf[nt] = *(const half8*)&Bs[(wn*64 + nt*16 + lr)*40 + lk*8];
    #pragma unroll
    for (int mt = 0; mt < 4; ++mt)
      #pragma unroll
      for (int nt = 0; nt < 4; ++nt)
        acc[mt][nt] = __builtin_amdgcn_mfma_f32_16x16x32_f16(af[mt], bf[nt], acc[mt][nt], 0, 0, 0);
  }
  const int rb = lk*4;
  #pragma unroll
  for (int mt = 0; mt < 4; ++mt) {
    #pragma unroll
    for (int nt = 0; nt < 4; ++nt) {
      int n = n0 + wn*64 + nt*16 + lr;
      int mloc = m0 + wm*64 + mt*16 + rb;
      int dir = n >> 10, cc = n & 1023;
      int gate = cc >> 8, u = cc & 255;
      float bs = (dir ? bias1 : bias0)[cc];
      f16* dst = Cx + (size_t)dir*dirStride;
      #pragma unroll
      for (int r = 0; r < 4; ++r)
        dst[(size_t)(mloc+r)*1024 + u*4 + gate] = (f16)(acc[mt][nt][r] + bs);
    }
  }
}

// ---------------- LSTM recurrence (lane k-sliced) — champion (R5) ----------------
// 1 WG (512 threads) per (e,d,b). Thread t: rg=t>>3 (row group), ks=t&7 (k-slice
// of 32). Rows r = rg*16+j, j=0..15: j<13 register-resident (208 dw, pinned),
// j=13..15 read from LDS each step (96 KB). No L2 weight streams.
#define RROWS 13
#define LROWS 3

__device__ __forceinline__ float dot8(float acc, uint4 wv, uint4 hv) {
#if __has_builtin(__builtin_amdgcn_fdot2)
  union { uint4 u; half2t h[4]; } W, Hh;
  W.u = wv; Hh.u = hv;
  #pragma unroll
  for (int i = 0; i < 4; ++i) acc = __builtin_amdgcn_fdot2(W.h[i], Hh.h[i], acc, false);
#else
  union { uint4 u; f16 h[8]; } W, Hh;
  W.u = wv; Hh.u = hv;
  #pragma unroll
  for (int i = 0; i < 8; ++i) acc += (float)W.h[i]*(float)Hh.h[i];
#endif
  return acc;
}

__device__ __forceinline__ float sigmoid_f(float x) {
  float e = __expf(-x);
  return __builtin_amdgcn_rcpf(1.f + e);
}
__device__ __forceinline__ float tanh_f(float x) {
  float e = __expf(2.f * x);
  return 1.f - 2.f * __builtin_amdgcn_rcpf(e + 1.f);
}

__device__ __forceinline__ void pin4(uint4& v) {
  asm volatile("" : "+v"(v.x), "+v"(v.y), "+v"(v.z), "+v"(v.w));
}

// DPP butterfly add over the 8-lane k-slice group (VALU pipe, no LDS).
template<int CTRL>
__device__ __forceinline__ float dpp_add(float v) {
  int m = __builtin_amdgcn_update_dpp(0, __builtin_bit_cast(int, v), CTRL, 0xf, 0xf, true);
  return v + __builtin_bit_cast(float, m);
}
__device__ __forceinline__ float reduce8(float v) {
  v = dpp_add<0xB1>(v);   // quad_perm [1,0,3,2]  : lane ^ 1
  v = dpp_add<0x4E>(v);   // quad_perm [2,3,0,1]  : lane ^ 2
  v = dpp_add<0x141>(v);  // row_half_mirror      : cross 4-group within 8
  return v;
}

__global__ __launch_bounds__(512, 2) void lstm_kernel(
    const f16* __restrict__ whh16,
    const f16* __restrict__ xg_raw, const f16* __restrict__ xg_sum,
    f16* __restrict__ out_raw, f16* __restrict__ out_sum)
{
  const int wg = blockIdx.x;               // [e(1)][d(1)][b(5)]
  const int e = wg >> 6, r2 = wg & 63, d = r2 >> 5, b = r2 & 31;
  const int S = e ? SSUM : SRAW;
  const int t = threadIdx.x;
  const int rg = t >> 3, ks = t & 7;
  const uint4* wb = (const uint4*)(whh16 + (size_t)(e*2+d)*(64*512*8));
  const f16* xg = (e ? xg_sum : xg_raw) + ((size_t)(d*32 + b))*(size_t)S*1024;
  f16* outp = (e ? out_sum : out_raw) + (size_t)b*S*512 + d*256;

  __shared__ __align__(16) uint4 wl[LROWS*4*512];   // 96 KB: rows 13..15
  __shared__ float pre[1024];                        // raw pre-activations
  __shared__ __align__(16) f16 hrep[4*264];          // 4 padded copies of h[256]

  // stage LDS weight rows (chunks 52..63)
  #pragma unroll
  for (int c = 0; c < LROWS*4; ++c) wl[c*512 + t] = wb[(RROWS*4 + c)*512 + t];
  // register weight rows 0..12 (chunks 0..51), pinned against rematerialization
  uint4 wr[RROWS*4];
  #pragma unroll
  for (int c = 0; c < RROWS*4; ++c) wr[c] = wb[c*512 + t];
  #pragma unroll
  for (int c = 0; c < RROWS*4; ++c) pin4(wr[c]);

  if (t < 256) {
    #pragma unroll
    for (int cpy = 0; cpy < 4; ++cpy) hrep[cpy*264 + t] = (f16)0.f;
  }
  float cst = 0.f;
  const int hbyte = (ks >> 1)*528 + ks*64;           // conflict-light slice base
  const int preS = ((rg >> 4) << 8) + ((rg & 15) << 4);  // gate*256 + ubase
  __syncthreads();

  for (int st = 0; st < S; ++st) {
    const int s = d ? (S - 1 - st) : st;

    // xg for this step (tail threads), consumed after the barrier
    uint2 xq;
    if (t < 256) xq = *(const uint2*)(xg + ((size_t)s*1024 + t*4));

    // h slice (32 elems) from replicated copy
    uint4 hv[4];
    #pragma unroll
    for (int q = 0; q < 4; ++q)
      hv[q] = *(const uint4*)((const char*)hrep + hbyte + q*16);

    float pa = 0.f, pb = 0.f;   // owned rows: j=ks and j=ks+8

    // register rows 0..12
    #pragma unroll
    for (int j = 0; j < RROWS; ++j) {
      float rs = 0.f;
      #pragma unroll
      for (int q = 0; q < 4; ++q) rs = dot8(rs, wr[j*4 + q], hv[q]);
      rs = reduce8(rs);
      if (j < 8) { pa = (ks == j) ? rs : pa; }
      else       { pb = (ks == j - 8) ? rs : pb; }
    }
    // LDS rows 13..15 (per-lane-distinct b128 reads; compiler pipelines lgkmcnt)
    #pragma unroll
    for (int j = 0; j < LROWS; ++j) {
      float rs = 0.f;
      #pragma unroll
      for (int q = 0; q < 4; ++q) rs = dot8(rs, wl[(j*4 + q)*512 + t], hv[q]);
      rs = reduce8(rs);
      pb = (ks == 5 + j) ? rs : pb;
    }

    pre[preS + ks]     = pa;
    pre[preS + 8 + ks] = pb;
    __syncthreads();

    if (t < 256) {
      half2t x01 = __builtin_bit_cast(half2t, xq.x);  // i, f
      half2t x23 = __builtin_bit_cast(half2t, xq.y);  // g, o
      float vi = pre[t]       + (float)x01[0];
      float vf = pre[256 + t] + (float)x01[1];
      float vg = pre[512 + t] + (float)x23[0];
      float vo = pre[768 + t] + (float)x23[1];
      float ig = sigmoid_f(vi);
      float fg = sigmoid_f(vf);
      float gg = tanh_f(vg);
      float og = sigmoid_f(vo);
      cst = fg*cst + ig*gg;
      float hval = og*tanh_f(cst);
      f16 hf = (f16)hval;
      #pragma unroll
      for (int cpy = 0; cpy < 4; ++cpy) hrep[cpy*264 + t] = hf;
      outp[(size_t)s*512 + t] = hf;
    }
    __syncthreads();
  }
}

// ---------------- mean pool + k,v projection ----------------
__global__ __launch_bounds__(256) void pool_kv_kernel(
    const f16* __restrict__ out_sum, const int* __restrict__ len_sum,
    const float* __restrict__ Wk, const float* __restrict__ Wv,
    float* __restrict__ kb, float* __restrict__ vb)
{
  const int b = blockIdx.x, t = threadIdx.x;
  __shared__ float sv[512];
  int len = len_sum[b]; if (len < 1) len = 1;
  float a0 = 0.f, a1 = 0.f;
  for (int s = 0; s < len; ++s) {
    const f16* row = out_sum + ((size_t)b*SSUM + s)*512;
    a0 += (float)row[t];
    a1 += (float)row[t+256];
  }
  float inv = 1.f/(float)len;
  sv[t] = a0*inv; sv[t+256] = a1*inv;
  __syncthreads();
  #pragma unroll
  for (int half = 0; half < 2; ++half) {
    int o = t + half*256;
    int h = o >> 7, dh = o & 127;
    const float* wkp = Wk + (size_t)h*512*128 + dh;
    const float* wvp = Wv + (size_t)h*512*128 + dh;
    float ak = 0.f, av = 0.f;
    for (int e2 = 0; e2 < 512; ++e2) {
      float sve = sv[e2];
      ak += sve*wkp[(size_t)e2*128];
      av += sve*wvp[(size_t)e2*128];
    }
    kb[((size_t)h*32 + b)*128 + dh] = ak;
    vb[((size_t)h*32 + b)*128 + dh] = av;
  }
}

// ---------------- scores + softmax + fused (out = q + attn*v) ----------------
__global__ __launch_bounds__(256) void attn_final_kernel(
    float* __restrict__ q, const float* __restrict__ kb, const float* __restrict__ vb)
{
  const int hb = blockIdx.x;          // h*32 + b
  const int h = hb >> 5, b = hb & 31;
  const int t = threadIdx.x;
  __shared__ __align__(16) float kk[128];
  __shared__ __align__(16) float vvs[128];
  __shared__ float att[1024];
  __shared__ float red[4];
  if (t < 128) kk[t] = kb[(size_t)hb*128 + t];
  else if (t < 256) vvs[t - 128] = vb[(size_t)hb*128 + (t - 128)];
  __syncthreads();
  float vals[4];
  #pragma unroll
  for (int i = 0; i < 4; ++i) {
    int s = t + i*256;
    const float4* qp = (const float4*)(q + ((size_t)b*1024 + s)*512 + h*128);
    const float4* kp = (const float4*)kk;
    float a = 0.f;
    #pragma unroll
    for (int e2 = 0; e2 < 32; ++e2) {
      float4 qq = qp[e2], kx = kp[e2];
      a += qq.x*kx.x + qq.y*kx.y + qq.z*kx.z + qq.w*kx.w;
    }
    vals[i] = a;
  }
  float m = fmaxf(fmaxf(vals[0], vals[1]), fmaxf(vals[2], vals[3]));
  for (int o = 1; o < 64; o <<= 1) m = fmaxf(m, __shfl_xor(m, o));
  if ((t & 63) == 0) red[t >> 6] = m;
  __syncthreads();
  m = fmaxf(fmaxf(red[0], red[1]), fmaxf(red[2], red[3]));
  __syncthreads();
  float ex[4], lsum = 0.f;
  #pragma unroll
  for (int i = 0; i < 4; ++i) { ex[i] = __expf(vals[i] - m); lsum += ex[i]; }
  for (int o = 1; o < 64; o <<= 1) lsum += __shfl_xor(lsum, o);
  if ((t & 63) == 0) red[t >> 6] = lsum;
  __syncthreads();
  float inv = 1.f/(red[0] + red[1] + red[2] + red[3]);
  #pragma unroll
  for (int i = 0; i < 4; ++i) att[t + i*256] = ex[i]*inv;
  __syncthreads();   // all q reads above complete; att/vvs ready

  // epilogue: out = q + att[s]*v, coalesced (32-lane groups own one s-row)
  const int sg = t >> 5, f4 = t & 31;
  const float4 vv4 = ((const float4*)vvs)[f4];
  for (int chunk = 0; chunk < 128; ++chunk) {
    int s = chunk*8 + sg;
    float a = att[s];
    float4* qp = (float4*)(q + ((size_t)b*1024 + s)*512 + h*128);
    float4 qq = qp[f4];
    qq.x += a*vv4.x; qq.y += a*vv4.y; qq.z += a*vv4.z; qq.w += a*vv4.w;
    qp[f4] = qq;
  }
}

// ---------------- launch ----------------
extern "C" void kernel_launch(void* const* d_in, const int* in_sizes, int n_in,
                              void* d_out, int out_size, void* d_ws, size_t ws_size,
                              hipStream_t stream)
{
  const float* in_raw = (const float*)d_in[0];
  const float* in_sum = (const float*)d_in[1];
  const int*  len_sum = (const int*)d_in[3];
  const float* rf_wih = (const float*)d_in[4];
  const float* rf_whh = (const float*)d_in[5];
  const float* rf_b   = (const float*)d_in[6];
  const float* rb_wih = (const float*)d_in[7];
  const float* rb_whh = (const float*)d_in[8];
  const float* rb_b   = (const float*)d_in[9];
  const float* sf_wih = (const float*)d_in[10];
  const float* sf_whh = (const float*)d_in[11];
  const float* sf_b   = (const float*)d_in[12];
  const float* sb_wih = (const float*)d_in[13];
  const float* sb_whh = (const float*)d_in[14];
  const float* sb_b   = (const float*)d_in[15];
  const float* wq     = (const float*)d_in[16];
  const float* wk     = (const float*)d_in[17];
  const float* wv     = (const float*)d_in[18];

  if (ws_size < WS_NEED) return;

  char* ws = (char*)d_ws;
  f16* xg_raw_p  = (f16*)(ws + OFF_XG_RAW);
  f16* xg_sum_p  = (f16*)(ws + OFF_XG_SUM);
  f16* out_raw_p = (f16*)(ws + OFF_OUT_RAW);
  f16* out_sum_p = (f16*)(ws + OFF_OUT_SUM);
  f16* a_raw_p   = (f16*)(ws + OFF_A_RAW);
  f16* a_sum_p   = (f16*)(ws + OFF_A_SUM);
  f16* bih_raw_p = (f16*)(ws + OFF_BIH_RAW);
  f16* bih_sum_p = (f16*)(ws + OFF_BIH_SUM);
  f16* whh16_p   = (f16*)(ws + OFF_WHH);
  f16* wq16_p    = (f16*)(ws + OFF_WQ);
  float* kb_p    = (float*)(ws + OFF_KB);
  float* vb_p    = (float*)(ws + OFF_VB);
  float* qout    = (float*)d_out;

  pack_kernel<<<4096, 256, 0, stream>>>(
      in_raw, in_sum, rf_wih, rb_wih, sf_wih, sb_wih,
      rf_whh, rb_whh, sf_whh, sb_whh, wq,
      a_raw_p, a_sum_p, bih_raw_p, bih_sum_p, whh16_p, wq16_p);

  gemm_dual_kernel<<<dim3(288, 16), 256, 0, stream>>>(
      a_raw_p, bih_raw_p, a_sum_p, bih_sum_p,
      xg_raw_p, xg_sum_p, rf_b, rb_b, sf_b, sb_b);

  lstm_kernel<<<128, 512, 0, stream>>>(whh16_p, xg_raw_p, xg_sum_p, out_raw_p, out_sum_p);

  gemm_kernel<<<dim3(256, 4), 256, 0, stream>>>(
      out_raw_p, wq16_p, qout, 512, 512);

  pool_kv_kernel<<<32, 256, 0, stream>>>(out_sum_p, len_sum, wk, wv, kb_p, vb_p);
  attn_final_kernel<<<128, 256, 0, stream>>>(qout, kb_p, vb_p);
}